// Round 11
// baseline (559.992 us; speedup 1.0000x reference)
//
#include <hip/hip_runtime.h>
#include <hip/hip_fp16.h>
#include <math.h>

#define NUM_GRAPHS 64

typedef unsigned short ushortT;
typedef __attribute__((ext_vector_type(8))) short bf16x8;
typedef __attribute__((ext_vector_type(4))) float f32x4;

// ---- static level tables ----
constexpr int cN[5]       = {20000, 10000, 5000, 2500, 1250};
constexpr int cE[5]       = {320000, 160000, 80000, 40000, 20000};
constexpr int cNOFF[6]    = {0, 20000, 30000, 35000, 37500, 38750};
constexpr int cEOFF[6]    = {0, 320000, 480000, 560000, 600000, 620000};
constexpr int cEBLKOFF[6] = {0, 1250, 1875, 2188, 2345, 2424};
constexpr int cNBLKOFF[6] = {0, 79, 119, 139, 149, 154};
constexpr int cMT[5]      = {5064, 2564, 1314, 689, 377};
constexpr int cTILEOFF[6] = {0, 5064, 7628, 8942, 9631, 10008};
constexpr int cSEOFF[6]   = {0, 324096, 488192, 572288, 616384, 640512};
constexpr int cF1OFF[6]   = {0, 640000, 1280000, 1600000, 1760000, 1840000};
constexpr int cWOFF[6]    = {0, 32000, 96000, 160000, 224000, 288000};
constexpr int cABLK[6]    = {0, 1250, 1875, 2188, 2345, 2424};   // ceil(N/16) prefix
constexpr int cRBOFF[5]   = {0, 256, 768, 1280, 1792};           // rootb swizzle uint4 offsets
constexpr int cRGB[6]     = {0, 313, 470, 549, 589, 609};        // ceil(N/64) prefix

struct P5f { const float* p[5]; };
struct P5i { const int* p[5]; };

__device__ __forceinline__ int lvl_e(int b) {
    return (b >= cEBLKOFF[4]) ? 4 : (b >= cEBLKOFF[3]) ? 3 : (b >= cEBLKOFF[2]) ? 2 : (b >= cEBLKOFF[1]) ? 1 : 0;
}
__device__ __forceinline__ int lvl_n(int b) {
    return (b >= cNBLKOFF[4]) ? 4 : (b >= cNBLKOFF[3]) ? 3 : (b >= cNBLKOFF[2]) ? 2 : (b >= cNBLKOFF[1]) ? 1 : 0;
}

__device__ __forceinline__ ushortT f2bf(float f) {
    union { float f; unsigned int u; } v; v.f = f;
    unsigned int r = (v.u + 0x7FFFu + ((v.u >> 16) & 1u)) >> 16;
    return (ushortT)r;
}
__device__ __forceinline__ float h2f_lo(unsigned int u) {
    return __half2float(__ushort_as_half((ushortT)(u & 0xFFFFu)));
}
__device__ __forceinline__ float h2f_hi(unsigned int u) {
    return __half2float(__ushort_as_half((ushortT)(u >> 16)));
}

// ---------------- prep: per-block cell histogram + dst degree count ----------------
__global__ void k_hist(P5f PS, P5i EI, int* __restrict__ dcnt, int* __restrict__ bb) {
    int b = blockIdx.x;
    int l = lvl_e(b);
    int lb = b - cEBLKOFF[l];
    int E = cE[l];
    __shared__ int h[64];
    int t = threadIdx.x;
    if (t < 64) h[t] = 0;
    __syncthreads();
    int e = lb * 256 + t;
    if (e < E) {
        atomicAdd(&dcnt[cNOFF[l] + EI.p[l][E + e]], 1);
        const float* ps = PS.p[l];
        int c = (int)floorf(ps[e * 3] * 4.f) * 16 + (int)floorf(ps[e * 3 + 1] * 4.f) * 4
              + (int)floorf(ps[e * 3 + 2] * 4.f);
        atomicAdd(&h[c], 1);
    }
    __syncthreads();
    if (t < 64) bb[(size_t)b * 64 + t] = h[t];
}

// ---------------- cell scan ----------------
__global__ void k_cellscan(int* __restrict__ bb_all, int* __restrict__ csPad,
                           int* __restrict__ cellTot, int* __restrict__ cot_all) {
    int l = blockIdx.x;
    int c = threadIdx.x;
    int* bb = bb_all + (size_t)cEBLKOFF[l] * 64;
    int nblk = cEBLKOFF[l + 1] - cEBLKOFF[l];
    int run = 0;
    int b = 0;
    for (; b + 16 <= nblk; b += 16) {
        int v[16];
#pragma unroll
        for (int u = 0; u < 16; u++) v[u] = bb[(b + u) * 64 + c];
#pragma unroll
        for (int u = 0; u < 16; u++) { bb[(b + u) * 64 + c] = run; run += v[u]; }
    }
    for (; b < nblk; b++) { int v = bb[b * 64 + c]; bb[b * 64 + c] = run; run += v; }
    int tot = run;
    cellTot[l * 64 + c] = tot;
    int tiles = (tot + 63) >> 6;
    int x = tiles;
#pragma unroll
    for (int off = 1; off < 64; off <<= 1) { int y = __shfl_up(x, off, 64); if (c >= off) x += y; }
    int tileBase = x - tiles;
    csPad[l * 64 + c] = tileBase * 64;
    int* cot = cot_all + cTILEOFF[l];
    for (int i = 0; i < tiles; i++) cot[tileBase + i] = c;
    int nT = __shfl(x, 63, 64);
    int mt = cMT[l];
    for (int i = nT + c; i < mt; i += 64) cot[i] = -1;
}

// ---------------- node-degree scans ----------------
__global__ void k_nscan1(const int* __restrict__ dcnt, int* __restrict__ dbase, int* __restrict__ bsum) {
    int b = blockIdx.x;
    int l = lvl_n(b);
    int lb = b - cNBLKOFF[l];
    int n = cN[l];
    __shared__ int sh[256];
    int t = threadIdx.x;
    int i = lb * 256 + t;
    int v = (i < n) ? dcnt[cNOFF[l] + i] : 0;
    sh[t] = v;
    __syncthreads();
    for (int off = 1; off < 256; off <<= 1) {
        int y = (t >= off) ? sh[t - off] : 0;
        __syncthreads();
        sh[t] += y;
        __syncthreads();
    }
    if (i < n) dbase[cNOFF[l] + i] = sh[t] - v;
    if (t == 255) bsum[b] = sh[255];
}

__global__ void k_nscan2(const int* __restrict__ bsum, int* __restrict__ boff) {
    int l = blockIdx.x;
    int o = cNBLKOFF[l];
    int nb = cNBLKOFF[l + 1] - o;
    int t = threadIdx.x;
    int v = (t < nb) ? bsum[o + t] : 0;
    int s = v;
#pragma unroll
    for (int off = 1; off < 64; off <<= 1) { int y = __shfl_up(s, off, 64); if (t >= off) s += y; }
    int tot = __shfl(s, 63, 64);
    if (t < nb) boff[o + t] = s - v;
    int t2 = t + 64;
    int v2 = (t2 < nb) ? bsum[o + t2] : 0;
    int s2 = v2;
#pragma unroll
    for (int off = 1; off < 64; off <<= 1) { int y = __shfl_up(s2, off, 64); if (t >= off) s2 += y; }
    if (t2 < nb) boff[o + t2] = tot + s2 - v2;
}

// ---- merged scatter: one edge pass -> cbrec (cell order), darec (dst order), cpos ----
__global__ void k_scatter(P5f PS, P5i EI, const int* __restrict__ bb, const int* __restrict__ csPad,
                          const int* __restrict__ dbase, const int* __restrict__ boff,
                          int* __restrict__ rank,
                          int4* __restrict__ cbrec, int4* __restrict__ darec,
                          int* __restrict__ cpos) {
    int b = blockIdx.x;
    int l = lvl_e(b);
    int lb = b - cEBLKOFF[l];
    int E = cE[l];
    __shared__ int base[64];
    __shared__ int cnt[64];
    int t = threadIdx.x;
    if (t < 64) { base[t] = bb[(size_t)b * 64 + t] + csPad[l * 64 + t]; cnt[t] = 0; }
    __syncthreads();
    int e = lb * 256 + t;
    if (e >= E) return;
    const float* ps = PS.p[l];
    float v0 = ps[e * 3] * 4.f, v1 = ps[e * 3 + 1] * 4.f, v2 = ps[e * 3 + 2] * 4.f;
    float f0 = floorf(v0), f1v = floorf(v1), f2v = floorf(v2);
    int c = (int)f0 * 16 + (int)f1v * 4 + (int)f2v;
    int r = atomicAdd(&cnt[c], 1);
    int posc = base[c] + r;
    const int* ei = EI.p[l];
    int src = ei[e];
    int dst = ei[E + e];
    int posd = dbase[cNOFF[l] + dst] + boff[cNBLKOFF[l] + (dst >> 8)]
             + atomicAdd(&rank[cNOFF[l] + dst], 1);
    unsigned int fxfy = (unsigned int)__half_as_ushort(__float2half(v0 - f0))
                      | ((unsigned int)__half_as_ushort(__float2half(v1 - f1v)) << 16);
    unsigned int fzp  = (unsigned int)__half_as_ushort(__float2half(v2 - f2v));
    int4 rc;
    rc.x = src; rc.y = 0; rc.z = (int)fxfy; rc.w = (int)fzp;
    cbrec[cSEOFF[l] + posc] = rc;
    int4 rd;
    rd.x = src | (dst << 16); rd.y = c; rd.z = (int)fxfy; rd.w = (int)fzp;
    darec[cEOFF[l] + posd] = rd;
    cpos[cEOFF[l] + posd] = posc;
}

// -------- W + rootb swizzle (fused): fp32 -> MFMA B-frag bf16 ----------
__global__ void k_wswz(P5f WB, P5f RootB, uint4* __restrict__ hi4, uint4* __restrict__ rb) {
    int idx = blockIdx.x * 256 + threadIdx.x;
    if (idx >= 290304) return;
    if (idx < 288000) {
        int l = (idx >= 224000) ? 4 : (idx >= 160000) ? 3 : (idx >= 96000) ? 2 : (idx >= 32000) ? 1 : 0;
        int local = idx - cWOFF[l];
        int T = l ? 2 : 1, C = l ? 64 : 32;
        int lane = local & 63;
        int blk = (local >> 6) & 3;
        int rest = local >> 8;
        int st = rest % T, s = rest / T;
        int q = lane >> 4, n = blk * 16 + (lane & 15);
        const float* W = WB.p[l];
        union { ushortT u[8]; uint4 v; } ph;
#pragma unroll
        for (int j = 0; j < 8; j++) {
            int k = st * 32 + q * 8 + j;
            ph.u[j] = f2bf(W[((size_t)s * C + k) * 64 + n]);
        }
        hi4[idx] = ph.v;
    } else {
        int id2 = idx - 288000;
        int l = (id2 >= 1792) ? 4 : (id2 >= 1280) ? 3 : (id2 >= 768) ? 2 : (id2 >= 256) ? 1 : 0;
        int local = id2 - cRBOFF[l];
        int lane = local & 63;
        int w = (local >> 6) & 3;
        int st = local >> 8;
        int q = lane >> 4, n = w * 16 + (lane & 15);
        const float* R = RootB.p[l];
        union { ushortT u[8]; uint4 v; } ph;
#pragma unroll
        for (int j = 0; j < 8; j++) {
            int k = st * 32 + q * 8 + j;
            ph.u[j] = f2bf(R[k * 64 + n]);
        }
        rb[id2] = ph.v;
    }
}

// ---- Fused Conv A: LDS-staged edges, corner-parallel, ILP'd S@Wa tail ---------------
template<int C1>
__device__ __forceinline__ void conv_a_gemm(const float* __restrict__ S, const float* __restrict__ Wa,
                                            const float* __restrict__ x, const float* __restrict__ ra,
                                            const float* __restrict__ ba, const int* __restrict__ dcl,
                                            int node0, int nn, ushortT* __restrict__ f1bfl, int t) {
    int ch = t % C1;
    int npp = 256 / C1;
    float bias = ba[ch];
    float root = ra[ch];
    for (int node = t / C1; node < nn; node += npp) {
        const float* Sr = S + node * 126;
        float s0 = 0.f, s1 = 0.f, s2 = 0.f, s3 = 0.f;
#pragma unroll
        for (int k = 0; k < 124; k += 4) {
            s0 = fmaf(Sr[k],     Wa[k * C1 + ch],       s0);
            s1 = fmaf(Sr[k + 1], Wa[(k + 1) * C1 + ch], s1);
            s2 = fmaf(Sr[k + 2], Wa[(k + 2) * C1 + ch], s2);
            s3 = fmaf(Sr[k + 3], Wa[(k + 3) * C1 + ch], s3);
        }
        float s = ((s0 + s1) + (s2 + s3)) + Sr[124] * Wa[124 * C1 + ch];
        int gnode = node0 + node;
        int dv = dcl[gnode];
        float d = (float)(dv > 1 ? dv : 1);
        float o = s / d + x[gnode] * root + bias;
        f1bfl[(size_t)gnode * C1 + ch] = f2bf(fmaxf(o, 0.f));
    }
}

__launch_bounds__(256)
__global__ void conv_a_fused(P5f X, P5f WA, P5f RootA, P5f BiasA,
                             const int4* __restrict__ darec,
                             const int* __restrict__ dbase, const int* __restrict__ boff,
                             const int* __restrict__ dcnt, ushortT* __restrict__ f1bf) {
    __shared__ float S[16 * 126];
    __shared__ int infoS[256];
    __shared__ unsigned int fxyS[256];
    __shared__ unsigned int fzS[256];
    __shared__ float xsS[256];
    int b = blockIdx.x;
    int l = (b >= cABLK[4]) ? 4 : (b >= cABLK[3]) ? 3 : (b >= cABLK[2]) ? 2 : (b >= cABLK[1]) ? 1 : 0;
    int node0 = (b - cABLK[l]) * 16;
    int n = cN[l];
    int nn = n - node0; if (nn > 16) nn = 16;
    int t = threadIdx.x;
    for (int i = t; i < 16 * 126; i += 256) S[i] = 0.f;
    const int* db = dbase + cNOFF[l];
    const int* bo = boff + cNBLKOFF[l];
    int estart = db[node0] + bo[node0 >> 8];
    int vend = node0 + nn;
    int eend = (vend >= n) ? cE[l] : (db[vend] + bo[vend >> 8]);
    const float* x = X.p[l];
    const int4* dr = darec + cEOFF[l];
    const int bx = t & 1, by = (t >> 1) & 1, bz = (t >> 2) & 1;
    for (int cs = estart; cs < eend; cs += 256) {
        int p = cs + t;
        if (p < eend) {
            int4 r = dr[p];
            infoS[t] = ((((unsigned int)r.x) >> 16) - node0) * 64 + r.y;
            fxyS[t] = (unsigned int)r.z;
            fzS[t] = (unsigned int)r.w;
            xsS[t] = x[r.x & 0xFFFF];
        }
        __syncthreads();
        int ne = eend - cs; if (ne > 256) ne = 256;
        for (int j = (t >> 3); j < ne; j += 32) {
            int info = infoS[j];
            int nl = info >> 6, cell = info & 63;
            unsigned int uz = fxyS[j];
            float fx = h2f_lo(uz), fy = h2f_hi(uz), fz = h2f_lo(fzS[j]);
            float xs = xsS[j];
            int cx = cell >> 4, cy = (cell >> 2) & 3, cz = cell & 3;
            int slot = (cx + bx) * 25 + (cy + by) * 5 + (cz + bz);
            float wc = (bx ? fx : 1.f - fx) * (by ? fy : 1.f - fy) * (bz ? fz : 1.f - fz);
            atomicAdd(&S[nl * 126 + slot], wc * xs);
        }
        __syncthreads();
    }
    if (l == 0)
        conv_a_gemm<32>(S, WA.p[0], X.p[0], RootA.p[0], BiasA.p[0], dcnt + cNOFF[0],
                        node0, nn, f1bf + cF1OFF[0], t);
    else
        conv_a_gemm<64>(S, WA.p[l], X.p[l], RootA.p[l], BiasA.p[l], dcnt + cNOFF[l],
                        node0, nn, f1bf + cF1OFF[l], t);
}

// ---- R-gemm: f2 = f1bf @ rootb (bf16 MFMA), per-64-node tiles -----------------------
__launch_bounds__(256)
__global__ void k_rgemm(const ushortT* __restrict__ f1bf, const uint4* __restrict__ rb,
                        float* __restrict__ f2) {
    int b = blockIdx.x;
    int l = (b >= cRGB[4]) ? 4 : (b >= cRGB[3]) ? 3 : (b >= cRGB[2]) ? 2 : (b >= cRGB[1]) ? 1 : 0;
    int node0 = (b - cRGB[l]) * 64;
    int n = cN[l];
    int nn = n - node0; if (nn > 64) nn = 64;
    int t = threadIdx.x;
    int lane = t & 63, w = t >> 6;
    int q = lane >> 4, m = lane & 15;
    const int CIN = l ? 64 : 32;
    const int T = l ? 2 : 1;
    const ushortT* fl = f1bf + cF1OFF[l];
    const uint4* rbl = rb + cRBOFF[l];
    f32x4 C[4];
#pragma unroll
    for (int mt = 0; mt < 4; mt++) C[mt] = (f32x4){0.f, 0.f, 0.f, 0.f};
    for (int st = 0; st < T; st++) {
        bf16x8 bh = __builtin_bit_cast(bf16x8, rbl[(st * 4 + w) * 64 + lane]);
#pragma unroll
        for (int mt = 0; mt < 4; mt++) {
            int row = 16 * mt + m;
            int nr = node0 + row; if (nr > n - 1) nr = n - 1;
            bf16x8 a = *(const bf16x8*)&fl[(size_t)nr * CIN + st * 32 + q * 8];
            C[mt] = __builtin_amdgcn_mfma_f32_16x16x32_bf16(a, bh, C[mt], 0, 0, 0);
        }
    }
#pragma unroll
    for (int mt = 0; mt < 4; mt++)
#pragma unroll
        for (int rr = 0; rr < 4; rr++) {
            int row = 16 * mt + q * 4 + rr;
            if (row < nn)
                f2[(size_t)(cNOFF[l] + node0 + row) * 64 + 16 * w + m] = C[mt][rr];
        }
}

// ---- Conv B: WAVE-AUTONOMOUS tile (no LDS/barriers), 4 col-blocks per wave ----------
template<int CIN>
__device__ __forceinline__ void conv_b_wave(
    const ushortT* __restrict__ f1bfl, const int4* __restrict__ cbrec_l,
    const uint4* __restrict__ whiL,
    int cell, int tb, int valid, __half* __restrict__ pout, int lane) {
    const int T = CIN / 32;
    int4 r;
    if (lane < valid) r = cbrec_l[tb + lane];
    else { r.x = 0; r.y = 0; r.z = 0; r.w = 0; }
    int mysrc = r.x;
    unsigned int uz = (unsigned int)r.z;
    float myfx = h2f_lo(uz), myfy = h2f_hi(uz), myfz = h2f_lo((unsigned int)r.w);
    int q = lane >> 4, m = lane & 15;

    // A fragments for all 64 rows, loaded ONCE per tile
    bf16x8 ahr[4][T];
#pragma unroll
    for (int mt = 0; mt < 4; mt++) {
        int src = __shfl(mysrc, 16 * mt + m, 64);
#pragma unroll
        for (int st = 0; st < T; st++)
            ahr[mt][st] = *(const bf16x8*)&f1bfl[(size_t)src * CIN + st * 32 + q * 8];
    }
    // per-output-row fracs via shuffle
    float fxr[16], fyr[16], fzr[16];
#pragma unroll
    for (int mt = 0; mt < 4; mt++)
#pragma unroll
        for (int rr = 0; rr < 4; rr++) {
            int row = 16 * mt + q * 4 + rr;
            int i16 = mt * 4 + rr;
            fxr[i16] = __shfl(myfx, row, 64);
            fyr[i16] = __shfl(myfy, row, 64);
            fzr[i16] = __shfl(myfz, row, 64);
        }
    int cx = cell >> 4, cy = (cell >> 2) & 3, cz = cell & 3;

#pragma unroll
    for (int w2 = 0; w2 < 4; w2++) {
        f32x4 acc[4];
#pragma unroll
        for (int mt = 0; mt < 4; mt++) acc[mt] = (f32x4){0.f, 0.f, 0.f, 0.f};
#pragma unroll
        for (int xy = 0; xy < 4; xy++) {
            const int bx = xy & 1, by = xy >> 1;
            int slot0 = (cx + bx) * 25 + (cy + by) * 5 + cz;
            f32x4 C0[4], C1[4];
#pragma unroll
            for (int mt = 0; mt < 4; mt++) {
                C0[mt] = (f32x4){0.f, 0.f, 0.f, 0.f};
                C1[mt] = (f32x4){0.f, 0.f, 0.f, 0.f};
            }
#pragma unroll
            for (int st = 0; st < T; st++) {
                bf16x8 b0 = __builtin_bit_cast(bf16x8, whiL[((size_t)(slot0 * T + st) * 4 + w2) * 64 + lane]);
                bf16x8 b1 = __builtin_bit_cast(bf16x8, whiL[((size_t)((slot0 + 1) * T + st) * 4 + w2) * 64 + lane]);
#pragma unroll
                for (int mt = 0; mt < 4; mt++) {
                    C0[mt] = __builtin_amdgcn_mfma_f32_16x16x32_bf16(ahr[mt][st], b0, C0[mt], 0, 0, 0);
                    C1[mt] = __builtin_amdgcn_mfma_f32_16x16x32_bf16(ahr[mt][st], b1, C1[mt], 0, 0, 0);
                }
            }
#pragma unroll
            for (int mt = 0; mt < 4; mt++)
#pragma unroll
                for (int rr = 0; rr < 4; rr++) {
                    int i16 = mt * 4 + rr;
                    float wxy = (bx ? fxr[i16] : 1.f - fxr[i16]) * (by ? fyr[i16] : 1.f - fyr[i16]);
                    float tt = fmaf(fzr[i16], C1[mt][rr], (1.f - fzr[i16]) * C0[mt][rr]);
                    acc[mt][rr] = fmaf(wxy, tt, acc[mt][rr]);
                }
        }
#pragma unroll
        for (int mt = 0; mt < 4; mt++)
#pragma unroll
            for (int rr = 0; rr < 4; rr++) {
                int row = 16 * mt + q * 4 + rr;
                pout[(size_t)(tb + row) * 64 + 16 * w2 + m] = __float2half(acc[mt][rr]);
            }
    }
}

__launch_bounds__(256)
__global__ void conv_b32w(const ushortT* __restrict__ f1bf, const int4* __restrict__ cbrec,
                          const uint4* __restrict__ whi,
                          const int* __restrict__ cot, const int* __restrict__ csPad,
                          const int* __restrict__ cellTot, __half* __restrict__ Ph) {
    int wv = blockIdx.x * 4 + (threadIdx.x >> 6);
    if (wv >= 5064) return;
    int cell = cot[wv];
    if (cell < 0) return;
    int tb = wv * 64;
    int valid = csPad[cell] + cellTot[cell] - tb;
    if (valid > 64) valid = 64;
    conv_b_wave<32>(f1bf, cbrec, whi, cell, tb, valid, Ph, threadIdx.x & 63);
}

__launch_bounds__(256)
__global__ void conv_b64w(const ushortT* __restrict__ f1bf, const int4* __restrict__ cbrec,
                          const uint4* __restrict__ whi,
                          const int* __restrict__ cot, const int* __restrict__ csPad,
                          const int* __restrict__ cellTot, __half* __restrict__ Ph) {
    const int TB2[4] = {0, 2564, 3878, 4567};
    int wv = blockIdx.x * 4 + (threadIdx.x >> 6);
    if (wv >= 4944) return;
    int li = (wv >= 4567) ? 3 : (wv >= 3878) ? 2 : (wv >= 2564) ? 1 : 0;
    int l = li + 1;
    int tile = wv - TB2[li];
    int cell = cot[cTILEOFF[l] + tile];
    if (cell < 0) return;
    int tb = tile * 64;
    int valid = csPad[l * 64 + cell] + cellTot[l * 64 + cell] - tb;
    if (valid > 64) valid = 64;
    conv_b_wave<64>(f1bf + cF1OFF[l], cbrec + cSEOFF[l], whi + cWOFF[l],
                    cell, tb, valid, Ph + (size_t)(cSEOFF[l] - 324096) * 64, threadIdx.x & 63);
}

// ---- fused node epilogue + readout: gather Ph + R + bias + relu + graph-run sums ----
__device__ __forceinline__ void node_read_run(
    const __half* __restrict__ PhL, const int* __restrict__ cposL,
    const int* __restrict__ dbaseL, const int* __restrict__ boffL,
    const int* __restrict__ dcntL, const float* __restrict__ f2L,
    const int* __restrict__ batchL, float biasv,
    float* __restrict__ hsumL, float* __restrict__ gcntL,
    int base, int nn, int lane) {
    int curg = -1; float hacc = 0.f; int crun = 0;
    for (int j = 0; j < nn; j++) {
        int node = base + j;
        int g = batchL[node];
        if (g != curg) {
            if (curg >= 0) {
                atomicAdd(&hsumL[curg * 320 + lane], hacc);
                if (lane == 0) atomicAdd(&gcntL[curg], (float)crun);
            }
            curg = g; hacc = 0.f; crun = 0;
        }
        int start = dbaseL[node] + boffL[node >> 8];
        int deg = dcntL[node];
        float s0 = 0.f, s1 = 0.f;
        int k = 0;
        for (; k + 2 <= deg; k += 2) {
            s0 += __half2float(PhL[(size_t)cposL[start + k] * 64 + lane]);
            s1 += __half2float(PhL[(size_t)cposL[start + k + 1] * 64 + lane]);
        }
        if (k < deg) s0 += __half2float(PhL[(size_t)cposL[start + k] * 64 + lane]);
        float s = (s0 + s1) / (float)(deg > 1 ? deg : 1)
                + f2L[(size_t)node * 64 + lane] + biasv;
        hacc += fmaxf(s, 0.f);
        crun++;
    }
    if (curg >= 0) {
        atomicAdd(&hsumL[curg * 320 + lane], hacc);
        if (lane == 0) atomicAdd(&gcntL[curg], (float)crun);
    }
}

__launch_bounds__(256)
__global__ void k_node1(const __half* __restrict__ Ph, const int* __restrict__ cpos,
                        const int* __restrict__ dbase, const int* __restrict__ boff,
                        const int* __restrict__ dcnt, const float* __restrict__ f2,
                        const float* __restrict__ biasb, const int* __restrict__ batch,
                        float* __restrict__ hsum, float* __restrict__ gcnt) {
    int lane = threadIdx.x & 63;
    int wv = blockIdx.x * 4 + (threadIdx.x >> 6);
    int base = wv * 8;
    if (base >= 20000) return;
    int nn = 20000 - base; if (nn > 8) nn = 8;
    node_read_run(Ph, cpos, dbase, boff, dcnt, f2, batch, biasb[lane],
                  hsum, gcnt, base, nn, lane);
}

__launch_bounds__(256)
__global__ void k_node2(const __half* __restrict__ Ph, const int* __restrict__ cpos,
                        const int* __restrict__ dbase, const int* __restrict__ boff,
                        const int* __restrict__ dcnt, const float* __restrict__ f2,
                        P5f BiasB, P5i Batch, float* __restrict__ hsum, float* __restrict__ gcnt) {
    const int NB[4] = {0, 1250, 1875, 2188};  // ceil(N/8) prefix for l1..4
    int lane = threadIdx.x & 63;
    int wv = blockIdx.x * 4 + (threadIdx.x >> 6);
    if (wv >= 2345) return;
    int li = (wv >= 2188) ? 3 : (wv >= 1875) ? 2 : (wv >= 1250) ? 1 : 0;
    int l = li + 1;
    int base = (wv - NB[li]) * 8;
    int n = cN[l];
    if (base >= n) return;
    int nn = n - base; if (nn > 8) nn = 8;
    node_read_run(Ph + (size_t)(cSEOFF[l] - 324096) * 64, cpos + cEOFF[l],
                  dbase + cNOFF[l], boff + cNBLKOFF[l], dcnt + cNOFF[l],
                  f2 + (size_t)cNOFF[l] * 64, Batch.p[l], BiasB.p[l][lane],
                  hsum + l * 64, gcnt + l * 64, base, nn, lane);
}

// ---------------- FC + log_softmax: one block per graph ----------------
__global__ void fc_kernel(const float* __restrict__ hsum, const float* __restrict__ gcnt,
                          const float* __restrict__ fcw, const float* __restrict__ fcb,
                          float* __restrict__ out) {
    int g = blockIdx.x;
    int lane = threadIdx.x;  // 64
    float partial[10];
#pragma unroll
    for (int t = 0; t < 10; t++) partial[t] = 0.f;
#pragma unroll
    for (int k = 0; k < 5; k++) {
        int j = k * 64 + lane;
        float c = fmaxf(gcnt[k * 64 + g], 1.f);
        float h = hsum[g * 320 + j] / c;
        const float* fw = fcw + j * 10;
#pragma unroll
        for (int t = 0; t < 10; t++) partial[t] = fmaf(h, fw[t], partial[t]);
    }
#pragma unroll
    for (int off = 32; off >= 1; off >>= 1)
#pragma unroll
        for (int t = 0; t < 10; t++) partial[t] += __shfl_xor(partial[t], off, 64);
    if (lane == 0) {
        float logit[10];
#pragma unroll
        for (int t = 0; t < 10; t++) logit[t] = partial[t] + fcb[t];
        float m = logit[0];
#pragma unroll
        for (int t = 1; t < 10; t++) m = fmaxf(m, logit[t]);
        float sum = 0.f;
#pragma unroll
        for (int t = 0; t < 10; t++) sum += expf(logit[t] - m);
        float lse = m + logf(sum);
#pragma unroll
        for (int t = 0; t < 10; t++) out[g * 10 + t] = logit[t] - lse;
    }
}

extern "C" void kernel_launch(void* const* d_in, const int* in_sizes, int n_in,
                              void* d_out, int out_size, void* d_ws, size_t ws_size,
                              hipStream_t stream) {
    int* wsI = (int*)d_ws;
    int*   dcnt  = wsI;                          // 38750
    int*   rank  = dcnt + 38750;                 // 38750
    float* hsum  = (float*)(rank + 38750);       // 20480  (note: hsum[g*320 + l*64 + lane])
    float* gcnt  = hsum + 20480;                 // 320
    float* f2    = gcnt + 320;                   // 2,480,000 (R from rgemm)
    int*   dbase = (int*)(f2 + 2480000);         // 38750
    int*   bsum  = dbase + 38750;                // 160
    int*   boff  = bsum + 160;                   // 160
    int*   cpos  = boff + 160;                   // 620000
    int*   bb    = cpos + 620000;                // 155136
    int*   csPad = bb + 155136;                  // 320
    int*   cellTot = csPad + 320;                // 320
    int*   cot   = cellTot + 320;                // 10008
    int4*  cbrec = (int4*)(((size_t)(cot + 10008) + 15) & ~(size_t)15);   // 640512 recs
    int4*  darec = cbrec + 640512;               // 620000 recs
    ushortT* f1bf = (ushortT*)(darec + 620000);  // 1,840,000 ushorts
    uint4* whi   = (uint4*)(((size_t)(f1bf + 1840000) + 15) & ~(size_t)15);  // 288000
    uint4* rbsw  = whi + 288000;                 // 2304
    __half* Ph   = (__half*)(rbsw + 2304);       // 324096 rows of 64 (~41.5MB, reused l0 vs l1-4)

    hipMemsetAsync(dcnt, 0, (size_t)(38750 * 2 + 20480 + 320) * sizeof(int), stream);

    P5f PS, X, WA, RootA, BiasA, WB, RootB, BiasB;
    P5i EI, Batch;
    for (int l = 0; l < 5; l++) {
        const int b = l * 10;
        X.p[l]     = (const float*)d_in[b + 0];
        PS.p[l]    = (const float*)d_in[b + 1];
        EI.p[l]    = (const int*)d_in[b + 2];
        Batch.p[l] = (const int*)d_in[b + 3];
        WA.p[l]    = (const float*)d_in[b + 4];
        RootA.p[l] = (const float*)d_in[b + 5];
        BiasA.p[l] = (const float*)d_in[b + 6];
        WB.p[l]    = (const float*)d_in[b + 7];
        RootB.p[l] = (const float*)d_in[b + 8];
        BiasB.p[l] = (const float*)d_in[b + 9];
    }

    // prep
    k_hist<<<2424, 256, 0, stream>>>(PS, EI, dcnt, bb);
    k_cellscan<<<5, 64, 0, stream>>>(bb, csPad, cellTot, cot);
    k_nscan1<<<154, 256, 0, stream>>>(dcnt, dbase, bsum);
    k_nscan2<<<5, 64, 0, stream>>>(bsum, boff);
    k_scatter<<<2424, 256, 0, stream>>>(PS, EI, bb, csPad, dbase, boff, rank,
                                        cbrec, darec, cpos);
    k_wswz<<<1134, 256, 0, stream>>>(WB, RootB, whi, rbsw);

    // conv A (all levels) -> f1bf only
    conv_a_fused<<<2424, 256, 0, stream>>>(X, WA, RootA, BiasA, darec,
                                           dbase, boff, dcnt, f1bf);

    // R = f1 @ rootb into f2 (MFMA)
    k_rgemm<<<609, 256, 0, stream>>>(f1bf, rbsw, f2);

    // conv B (wave-autonomous) + fused node-epilogue/readout; Ph reused l0 vs l1-4
    conv_b32w<<<1266, 256, 0, stream>>>(f1bf, cbrec, whi, cot, csPad, cellTot, Ph);
    k_node1<<<625, 256, 0, stream>>>(Ph, cpos, dbase, boff, dcnt, f2, BiasB.p[0],
                                     Batch.p[0], hsum, gcnt);
    conv_b64w<<<1236, 256, 0, stream>>>(f1bf, cbrec, whi, cot, csPad, cellTot, Ph);
    k_node2<<<587, 256, 0, stream>>>(Ph, cpos, dbase, boff, dcnt, f2, BiasB, Batch,
                                     hsum, gcnt);

    // FC
    fc_kernel<<<64, 64, 0, stream>>>(hsum, gcnt, (const float*)d_in[50], (const float*)d_in[51],
                                     (float*)d_out);
}

// Round 12
// 535.934 us; speedup vs baseline: 1.0449x; 1.0449x over previous
//
#include <hip/hip_runtime.h>
#include <hip/hip_fp16.h>
#include <math.h>

#define NUM_GRAPHS 64

typedef unsigned short ushortT;
typedef __attribute__((ext_vector_type(8))) short bf16x8;
typedef __attribute__((ext_vector_type(4))) float f32x4;

// ---- static level tables ----
constexpr int cN[5]       = {20000, 10000, 5000, 2500, 1250};
constexpr int cE[5]       = {320000, 160000, 80000, 40000, 20000};
constexpr int cNOFF[6]    = {0, 20000, 30000, 35000, 37500, 38750};
constexpr int cEOFF[6]    = {0, 320000, 480000, 560000, 600000, 620000};
constexpr int cEBLKOFF[6] = {0, 1250, 1875, 2188, 2345, 2424};
constexpr int cNBLKOFF[6] = {0, 79, 119, 139, 149, 154};
constexpr int cMT[5]      = {5064, 2564, 1314, 689, 377};
constexpr int cTILEOFF[6] = {0, 5064, 7628, 8942, 9631, 10008};
constexpr int cSEOFF[6]   = {0, 324096, 488192, 572288, 616384, 640512};
constexpr int cF1OFF[6]   = {0, 640000, 1280000, 1600000, 1760000, 1840000};
constexpr int cWOFF[6]    = {0, 32000, 96000, 160000, 224000, 288000};
constexpr int cABLK[6]    = {0, 1250, 1875, 2188, 2345, 2424};   // ceil(N/16) prefix
constexpr int cRBOFF[5]   = {0, 256, 768, 1280, 1792};           // rootb swizzle uint4 offsets
constexpr int cRGB[6]     = {0, 313, 470, 549, 589, 609};        // ceil(N/64) prefix

struct P5f { const float* p[5]; };
struct P5i { const int* p[5]; };

__device__ __forceinline__ int lvl_e(int b) {
    return (b >= cEBLKOFF[4]) ? 4 : (b >= cEBLKOFF[3]) ? 3 : (b >= cEBLKOFF[2]) ? 2 : (b >= cEBLKOFF[1]) ? 1 : 0;
}
__device__ __forceinline__ int lvl_n(int b) {
    return (b >= cNBLKOFF[4]) ? 4 : (b >= cNBLKOFF[3]) ? 3 : (b >= cNBLKOFF[2]) ? 2 : (b >= cNBLKOFF[1]) ? 1 : 0;
}

__device__ __forceinline__ ushortT f2bf(float f) {
    union { float f; unsigned int u; } v; v.f = f;
    unsigned int r = (v.u + 0x7FFFu + ((v.u >> 16) & 1u)) >> 16;
    return (ushortT)r;
}
__device__ __forceinline__ float h2f_lo(unsigned int u) {
    return __half2float(__ushort_as_half((ushortT)(u & 0xFFFFu)));
}
__device__ __forceinline__ float h2f_hi(unsigned int u) {
    return __half2float(__ushort_as_half((ushortT)(u >> 16)));
}

// ---------------- prep: per-block cell histogram + dst degree count ----------------
__global__ void k_hist(P5f PS, P5i EI, int* __restrict__ dcnt, int* __restrict__ bb) {
    int b = blockIdx.x;
    int l = lvl_e(b);
    int lb = b - cEBLKOFF[l];
    int E = cE[l];
    __shared__ int h[64];
    int t = threadIdx.x;
    if (t < 64) h[t] = 0;
    __syncthreads();
    int e = lb * 256 + t;
    if (e < E) {
        atomicAdd(&dcnt[cNOFF[l] + EI.p[l][E + e]], 1);
        const float* ps = PS.p[l];
        int c = (int)floorf(ps[e * 3] * 4.f) * 16 + (int)floorf(ps[e * 3 + 1] * 4.f) * 4
              + (int)floorf(ps[e * 3 + 2] * 4.f);
        atomicAdd(&h[c], 1);
    }
    __syncthreads();
    if (t < 64) bb[(size_t)b * 64 + t] = h[t];
}

// ---------------- cell scan ----------------
__global__ void k_cellscan(int* __restrict__ bb_all, int* __restrict__ csPad,
                           int* __restrict__ cellTot, int* __restrict__ cot_all) {
    int l = blockIdx.x;
    int c = threadIdx.x;
    int* bb = bb_all + (size_t)cEBLKOFF[l] * 64;
    int nblk = cEBLKOFF[l + 1] - cEBLKOFF[l];
    int run = 0;
    int b = 0;
    for (; b + 16 <= nblk; b += 16) {
        int v[16];
#pragma unroll
        for (int u = 0; u < 16; u++) v[u] = bb[(b + u) * 64 + c];
#pragma unroll
        for (int u = 0; u < 16; u++) { bb[(b + u) * 64 + c] = run; run += v[u]; }
    }
    for (; b < nblk; b++) { int v = bb[b * 64 + c]; bb[b * 64 + c] = run; run += v; }
    int tot = run;
    cellTot[l * 64 + c] = tot;
    int tiles = (tot + 63) >> 6;
    int x = tiles;
#pragma unroll
    for (int off = 1; off < 64; off <<= 1) { int y = __shfl_up(x, off, 64); if (c >= off) x += y; }
    int tileBase = x - tiles;
    csPad[l * 64 + c] = tileBase * 64;
    int* cot = cot_all + cTILEOFF[l];
    for (int i = 0; i < tiles; i++) cot[tileBase + i] = c;
    int nT = __shfl(x, 63, 64);
    int mt = cMT[l];
    for (int i = nT + c; i < mt; i += 64) cot[i] = -1;
}

// ---------------- node-degree scans ----------------
__global__ void k_nscan1(const int* __restrict__ dcnt, int* __restrict__ dbase, int* __restrict__ bsum) {
    int b = blockIdx.x;
    int l = lvl_n(b);
    int lb = b - cNBLKOFF[l];
    int n = cN[l];
    __shared__ int sh[256];
    int t = threadIdx.x;
    int i = lb * 256 + t;
    int v = (i < n) ? dcnt[cNOFF[l] + i] : 0;
    sh[t] = v;
    __syncthreads();
    for (int off = 1; off < 256; off <<= 1) {
        int y = (t >= off) ? sh[t - off] : 0;
        __syncthreads();
        sh[t] += y;
        __syncthreads();
    }
    if (i < n) dbase[cNOFF[l] + i] = sh[t] - v;
    if (t == 255) bsum[b] = sh[255];
}

__global__ void k_nscan2(const int* __restrict__ bsum, int* __restrict__ boff) {
    int l = blockIdx.x;
    int o = cNBLKOFF[l];
    int nb = cNBLKOFF[l + 1] - o;
    int t = threadIdx.x;
    int v = (t < nb) ? bsum[o + t] : 0;
    int s = v;
#pragma unroll
    for (int off = 1; off < 64; off <<= 1) { int y = __shfl_up(s, off, 64); if (t >= off) s += y; }
    int tot = __shfl(s, 63, 64);
    if (t < nb) boff[o + t] = s - v;
    int t2 = t + 64;
    int v2 = (t2 < nb) ? bsum[o + t2] : 0;
    int s2 = v2;
#pragma unroll
    for (int off = 1; off < 64; off <<= 1) { int y = __shfl_up(s2, off, 64); if (t >= off) s2 += y; }
    if (t2 < nb) boff[o + t2] = tot + s2 - v2;
}

// ---- merged scatter: one edge pass -> cbrec (cell order), darec (dst order), cpos ----
__global__ void k_scatter(P5f PS, P5i EI, const int* __restrict__ bb, const int* __restrict__ csPad,
                          const int* __restrict__ dbase, const int* __restrict__ boff,
                          int* __restrict__ rank,
                          int4* __restrict__ cbrec, int4* __restrict__ darec,
                          int* __restrict__ cpos) {
    int b = blockIdx.x;
    int l = lvl_e(b);
    int lb = b - cEBLKOFF[l];
    int E = cE[l];
    __shared__ int base[64];
    __shared__ int cnt[64];
    int t = threadIdx.x;
    if (t < 64) { base[t] = bb[(size_t)b * 64 + t] + csPad[l * 64 + t]; cnt[t] = 0; }
    __syncthreads();
    int e = lb * 256 + t;
    if (e >= E) return;
    const float* ps = PS.p[l];
    float v0 = ps[e * 3] * 4.f, v1 = ps[e * 3 + 1] * 4.f, v2 = ps[e * 3 + 2] * 4.f;
    float f0 = floorf(v0), f1v = floorf(v1), f2v = floorf(v2);
    int c = (int)f0 * 16 + (int)f1v * 4 + (int)f2v;
    int r = atomicAdd(&cnt[c], 1);
    int posc = base[c] + r;
    const int* ei = EI.p[l];
    int src = ei[e];
    int dst = ei[E + e];
    int posd = dbase[cNOFF[l] + dst] + boff[cNBLKOFF[l] + (dst >> 8)]
             + atomicAdd(&rank[cNOFF[l] + dst], 1);
    unsigned int fxfy = (unsigned int)__half_as_ushort(__float2half(v0 - f0))
                      | ((unsigned int)__half_as_ushort(__float2half(v1 - f1v)) << 16);
    unsigned int fzp  = (unsigned int)__half_as_ushort(__float2half(v2 - f2v));
    int4 rc;
    rc.x = src; rc.y = 0; rc.z = (int)fxfy; rc.w = (int)fzp;
    cbrec[cSEOFF[l] + posc] = rc;
    int4 rd;
    rd.x = src | (dst << 16); rd.y = c; rd.z = (int)fxfy; rd.w = (int)fzp;
    darec[cEOFF[l] + posd] = rd;
    cpos[cEOFF[l] + posd] = posc;
}

// -------- W + rootb swizzle (fused): fp32 -> MFMA B-frag bf16 ----------
__global__ void k_wswz(P5f WB, P5f RootB, uint4* __restrict__ hi4, uint4* __restrict__ rb) {
    int idx = blockIdx.x * 256 + threadIdx.x;
    if (idx >= 290304) return;
    if (idx < 288000) {
        int l = (idx >= 224000) ? 4 : (idx >= 160000) ? 3 : (idx >= 96000) ? 2 : (idx >= 32000) ? 1 : 0;
        int local = idx - cWOFF[l];
        int T = l ? 2 : 1, C = l ? 64 : 32;
        int lane = local & 63;
        int blk = (local >> 6) & 3;
        int rest = local >> 8;
        int st = rest % T, s = rest / T;
        int q = lane >> 4, n = blk * 16 + (lane & 15);
        const float* W = WB.p[l];
        union { ushortT u[8]; uint4 v; } ph;
#pragma unroll
        for (int j = 0; j < 8; j++) {
            int k = st * 32 + q * 8 + j;
            ph.u[j] = f2bf(W[((size_t)s * C + k) * 64 + n]);
        }
        hi4[idx] = ph.v;
    } else {
        int id2 = idx - 288000;
        int l = (id2 >= 1792) ? 4 : (id2 >= 1280) ? 3 : (id2 >= 768) ? 2 : (id2 >= 256) ? 1 : 0;
        int local = id2 - cRBOFF[l];
        int lane = local & 63;
        int w = (local >> 6) & 3;
        int st = local >> 8;
        int q = lane >> 4, n = w * 16 + (lane & 15);
        const float* R = RootB.p[l];
        union { ushortT u[8]; uint4 v; } ph;
#pragma unroll
        for (int j = 0; j < 8; j++) {
            int k = st * 32 + q * 8 + j;
            ph.u[j] = f2bf(R[k * 64 + n]);
        }
        rb[id2] = ph.v;
    }
}

// ---- Fused Conv A: LDS-staged edges, corner-parallel, ILP'd S@Wa tail ---------------
template<int C1>
__device__ __forceinline__ void conv_a_gemm(const float* __restrict__ S, const float* __restrict__ Wa,
                                            const float* __restrict__ x, const float* __restrict__ ra,
                                            const float* __restrict__ ba, const int* __restrict__ dcl,
                                            int node0, int nn, ushortT* __restrict__ f1bfl, int t) {
    int ch = t % C1;
    int npp = 256 / C1;
    float bias = ba[ch];
    float root = ra[ch];
    for (int node = t / C1; node < nn; node += npp) {
        const float* Sr = S + node * 126;
        float s0 = 0.f, s1 = 0.f, s2 = 0.f, s3 = 0.f;
#pragma unroll
        for (int k = 0; k < 124; k += 4) {
            s0 = fmaf(Sr[k],     Wa[k * C1 + ch],       s0);
            s1 = fmaf(Sr[k + 1], Wa[(k + 1) * C1 + ch], s1);
            s2 = fmaf(Sr[k + 2], Wa[(k + 2) * C1 + ch], s2);
            s3 = fmaf(Sr[k + 3], Wa[(k + 3) * C1 + ch], s3);
        }
        float s = ((s0 + s1) + (s2 + s3)) + Sr[124] * Wa[124 * C1 + ch];
        int gnode = node0 + node;
        int dv = dcl[gnode];
        float d = (float)(dv > 1 ? dv : 1);
        float o = s / d + x[gnode] * root + bias;
        f1bfl[(size_t)gnode * C1 + ch] = f2bf(fmaxf(o, 0.f));
    }
}

__launch_bounds__(256)
__global__ void conv_a_fused(P5f X, P5f WA, P5f RootA, P5f BiasA,
                             const int4* __restrict__ darec,
                             const int* __restrict__ dbase, const int* __restrict__ boff,
                             const int* __restrict__ dcnt, ushortT* __restrict__ f1bf) {
    __shared__ float S[16 * 126];
    __shared__ int infoS[256];
    __shared__ unsigned int fxyS[256];
    __shared__ unsigned int fzS[256];
    __shared__ float xsS[256];
    int b = blockIdx.x;
    int l = (b >= cABLK[4]) ? 4 : (b >= cABLK[3]) ? 3 : (b >= cABLK[2]) ? 2 : (b >= cABLK[1]) ? 1 : 0;
    int node0 = (b - cABLK[l]) * 16;
    int n = cN[l];
    int nn = n - node0; if (nn > 16) nn = 16;
    int t = threadIdx.x;
    for (int i = t; i < 16 * 126; i += 256) S[i] = 0.f;
    const int* db = dbase + cNOFF[l];
    const int* bo = boff + cNBLKOFF[l];
    int estart = db[node0] + bo[node0 >> 8];
    int vend = node0 + nn;
    int eend = (vend >= n) ? cE[l] : (db[vend] + bo[vend >> 8]);
    const float* x = X.p[l];
    const int4* dr = darec + cEOFF[l];
    const int bx = t & 1, by = (t >> 1) & 1, bz = (t >> 2) & 1;
    for (int cs = estart; cs < eend; cs += 256) {
        int p = cs + t;
        if (p < eend) {
            int4 r = dr[p];
            infoS[t] = ((((unsigned int)r.x) >> 16) - node0) * 64 + r.y;
            fxyS[t] = (unsigned int)r.z;
            fzS[t] = (unsigned int)r.w;
            xsS[t] = x[r.x & 0xFFFF];
        }
        __syncthreads();
        int ne = eend - cs; if (ne > 256) ne = 256;
        for (int j = (t >> 3); j < ne; j += 32) {
            int info = infoS[j];
            int nl = info >> 6, cell = info & 63;
            unsigned int uz = fxyS[j];
            float fx = h2f_lo(uz), fy = h2f_hi(uz), fz = h2f_lo(fzS[j]);
            float xs = xsS[j];
            int cx = cell >> 4, cy = (cell >> 2) & 3, cz = cell & 3;
            int slot = (cx + bx) * 25 + (cy + by) * 5 + (cz + bz);
            float wc = (bx ? fx : 1.f - fx) * (by ? fy : 1.f - fy) * (bz ? fz : 1.f - fz);
            atomicAdd(&S[nl * 126 + slot], wc * xs);
        }
        __syncthreads();
    }
    if (l == 0)
        conv_a_gemm<32>(S, WA.p[0], X.p[0], RootA.p[0], BiasA.p[0], dcnt + cNOFF[0],
                        node0, nn, f1bf + cF1OFF[0], t);
    else
        conv_a_gemm<64>(S, WA.p[l], X.p[l], RootA.p[l], BiasA.p[l], dcnt + cNOFF[l],
                        node0, nn, f1bf + cF1OFF[l], t);
}

// ---- R-gemm: f2 = f1bf @ rootb (bf16 MFMA), per-64-node tiles -----------------------
__launch_bounds__(256)
__global__ void k_rgemm(const ushortT* __restrict__ f1bf, const uint4* __restrict__ rb,
                        float* __restrict__ f2) {
    int b = blockIdx.x;
    int l = (b >= cRGB[4]) ? 4 : (b >= cRGB[3]) ? 3 : (b >= cRGB[2]) ? 2 : (b >= cRGB[1]) ? 1 : 0;
    int node0 = (b - cRGB[l]) * 64;
    int n = cN[l];
    int nn = n - node0; if (nn > 64) nn = 64;
    int t = threadIdx.x;
    int lane = t & 63, w = t >> 6;
    int q = lane >> 4, m = lane & 15;
    const int CIN = l ? 64 : 32;
    const int T = l ? 2 : 1;
    const ushortT* fl = f1bf + cF1OFF[l];
    const uint4* rbl = rb + cRBOFF[l];
    f32x4 C[4];
#pragma unroll
    for (int mt = 0; mt < 4; mt++) C[mt] = (f32x4){0.f, 0.f, 0.f, 0.f};
    for (int st = 0; st < T; st++) {
        bf16x8 bh = __builtin_bit_cast(bf16x8, rbl[(st * 4 + w) * 64 + lane]);
#pragma unroll
        for (int mt = 0; mt < 4; mt++) {
            int row = 16 * mt + m;
            int nr = node0 + row; if (nr > n - 1) nr = n - 1;
            bf16x8 a = *(const bf16x8*)&fl[(size_t)nr * CIN + st * 32 + q * 8];
            C[mt] = __builtin_amdgcn_mfma_f32_16x16x32_bf16(a, bh, C[mt], 0, 0, 0);
        }
    }
#pragma unroll
    for (int mt = 0; mt < 4; mt++)
#pragma unroll
        for (int rr = 0; rr < 4; rr++) {
            int row = 16 * mt + q * 4 + rr;
            if (row < nn)
                f2[(size_t)(cNOFF[l] + node0 + row) * 64 + 16 * w + m] = C[mt][rr];
        }
}

// ---- Conv B tile: block-per-tile (4 waves share tile), z-paired epilogue ------------
template<int CIN>
__device__ __forceinline__ void conv_b_tile(
    const ushortT* __restrict__ f1bfl, const int4* __restrict__ cbrec_l,
    const uint4* __restrict__ whiL,
    int cell, int tb, int valid, __half* __restrict__ pout,
    float* fxs, float* fys, float* fzs, int* srcs) {
    const int T = CIN / 32;
    int t = threadIdx.x;
    if (t < 64) {
        bool v = t < valid;
        int4 r;
        if (v) r = cbrec_l[tb + t]; else { r.x = 0; r.y = 0; r.z = 0; r.w = 0; }
        srcs[t] = r.x;
        unsigned int uz = (unsigned int)r.z;
        fxs[t] = h2f_lo(uz);
        fys[t] = h2f_hi(uz);
        fzs[t] = h2f_lo((unsigned int)r.w);
    }
    __syncthreads();

    int lane = t & 63, w = t >> 6;
    int q = lane >> 4, m = lane & 15;

    bf16x8 ahr[4][T];
#pragma unroll
    for (int mt = 0; mt < 4; mt++) {
        int src = srcs[16 * mt + m];
#pragma unroll
        for (int st = 0; st < T; st++)
            ahr[mt][st] = *(const bf16x8*)&f1bfl[(size_t)src * CIN + st * 32 + q * 8];
    }
    float fxr[16], fyr[16], fzr[16], gzr[16];
#pragma unroll
    for (int mt = 0; mt < 4; mt++)
#pragma unroll
        for (int rr = 0; rr < 4; rr++) {
            int row = 16 * mt + q * 4 + rr;
            fxr[mt * 4 + rr] = fxs[row];
            fyr[mt * 4 + rr] = fys[row];
            float fz = fzs[row];
            fzr[mt * 4 + rr] = fz;
            gzr[mt * 4 + rr] = 1.f - fz;
        }
    int cx = cell >> 4, cy = (cell >> 2) & 3, cz = cell & 3;
    f32x4 acc[4];
#pragma unroll
    for (int mt = 0; mt < 4; mt++) acc[mt] = (f32x4){0.f, 0.f, 0.f, 0.f};

#pragma unroll
    for (int xy = 0; xy < 4; xy++) {
        const int bx = xy & 1, by = xy >> 1;
        int slot0 = (cx + bx) * 25 + (cy + by) * 5 + cz;  // bz=0; bz=1 is slot0+1
        f32x4 C0[4], C1[4];
#pragma unroll
        for (int mt = 0; mt < 4; mt++) {
            C0[mt] = (f32x4){0.f, 0.f, 0.f, 0.f};
            C1[mt] = (f32x4){0.f, 0.f, 0.f, 0.f};
        }
#pragma unroll
        for (int st = 0; st < T; st++) {
            bf16x8 b0 = __builtin_bit_cast(bf16x8, whiL[((size_t)(slot0 * T + st) * 4 + w) * 64 + lane]);
            bf16x8 b1 = __builtin_bit_cast(bf16x8, whiL[((size_t)((slot0 + 1) * T + st) * 4 + w) * 64 + lane]);
#pragma unroll
            for (int mt = 0; mt < 4; mt++) {
                C0[mt] = __builtin_amdgcn_mfma_f32_16x16x32_bf16(ahr[mt][st], b0, C0[mt], 0, 0, 0);
                C1[mt] = __builtin_amdgcn_mfma_f32_16x16x32_bf16(ahr[mt][st], b1, C1[mt], 0, 0, 0);
            }
        }
#pragma unroll
        for (int mt = 0; mt < 4; mt++)
#pragma unroll
            for (int rr = 0; rr < 4; rr++) {
                int i16 = mt * 4 + rr;
                float wxy = (bx ? fxr[i16] : 1.f - fxr[i16]) * (by ? fyr[i16] : 1.f - fyr[i16]);
                float tt = fmaf(fzr[i16], C1[mt][rr], gzr[i16] * C0[mt][rr]);
                acc[mt][rr] = fmaf(wxy, tt, acc[mt][rr]);
            }
    }
    // coalesced cell-order store
#pragma unroll
    for (int mt = 0; mt < 4; mt++)
#pragma unroll
        for (int rr = 0; rr < 4; rr++) {
            int row = 16 * mt + q * 4 + rr;
            pout[(size_t)(tb + row) * 64 + 16 * w + m] = __float2half(acc[mt][rr]);
        }
}

__launch_bounds__(256)
__global__ void conv_b32(const ushortT* __restrict__ f1bf, const int4* __restrict__ cbrec,
                         const uint4* __restrict__ whi,
                         const int* __restrict__ cot, const int* __restrict__ csPad,
                         const int* __restrict__ cellTot, __half* __restrict__ Ph) {
    __shared__ float fxs[64], fys[64], fzs[64];
    __shared__ int srcs[64];
    int tile = blockIdx.x;
    int cell = cot[tile];
    if (cell < 0) return;
    int tb = tile * 64;
    int valid = csPad[cell] + cellTot[cell] - tb;
    if (valid > 64) valid = 64;
    conv_b_tile<32>(f1bf, cbrec, whi, cell, tb, valid, Ph, fxs, fys, fzs, srcs);
}

__launch_bounds__(256)
__global__ void conv_b64(const ushortT* __restrict__ f1bf, const int4* __restrict__ cbrec,
                         const uint4* __restrict__ whi,
                         const int* __restrict__ cot, const int* __restrict__ csPad,
                         const int* __restrict__ cellTot, __half* __restrict__ Ph) {
    __shared__ float fxs[64], fys[64], fzs[64];
    __shared__ int srcs[64];
    const int TB2[4] = {0, 2564, 3878, 4567};
    int blk = blockIdx.x;
    int li = (blk >= 4567) ? 3 : (blk >= 3878) ? 2 : (blk >= 2564) ? 1 : 0;
    int l = li + 1;
    int tile = blk - TB2[li];
    int cell = cot[cTILEOFF[l] + tile];
    if (cell < 0) return;
    int tb = tile * 64;
    int valid = csPad[l * 64 + cell] + cellTot[l * 64 + cell] - tb;
    if (valid > 64) valid = 64;
    conv_b_tile<64>(f1bf + cF1OFF[l], cbrec + cSEOFF[l], whi + cWOFF[l],
                    cell, tb, valid, Ph + (size_t)(cSEOFF[l] - 324096) * 64,
                    fxs, fys, fzs, srcs);
}

// ---- fused node epilogue + readout: gather Ph + R + bias + relu + graph-run sums ----
__device__ __forceinline__ void node_read_run(
    const __half* __restrict__ PhL, const int* __restrict__ cposL,
    const int* __restrict__ dbaseL, const int* __restrict__ boffL,
    const int* __restrict__ dcntL, const float* __restrict__ f2L,
    const int* __restrict__ batchL, float biasv,
    float* __restrict__ hsumL, float* __restrict__ gcntL,
    int base, int nn, int lane) {
    int curg = -1; float hacc = 0.f; int crun = 0;
    for (int j = 0; j < nn; j++) {
        int node = base + j;
        int g = batchL[node];
        if (g != curg) {
            if (curg >= 0) {
                atomicAdd(&hsumL[curg * 320 + lane], hacc);
                if (lane == 0) atomicAdd(&gcntL[curg], (float)crun);
            }
            curg = g; hacc = 0.f; crun = 0;
        }
        int start = dbaseL[node] + boffL[node >> 8];
        int deg = dcntL[node];
        float s0 = 0.f, s1 = 0.f;
        int k = 0;
        for (; k + 2 <= deg; k += 2) {
            s0 += __half2float(PhL[(size_t)cposL[start + k] * 64 + lane]);
            s1 += __half2float(PhL[(size_t)cposL[start + k + 1] * 64 + lane]);
        }
        if (k < deg) s0 += __half2float(PhL[(size_t)cposL[start + k] * 64 + lane]);
        float s = (s0 + s1) / (float)(deg > 1 ? deg : 1)
                + f2L[(size_t)node * 64 + lane] + biasv;
        hacc += fmaxf(s, 0.f);
        crun++;
    }
    if (curg >= 0) {
        atomicAdd(&hsumL[curg * 320 + lane], hacc);
        if (lane == 0) atomicAdd(&gcntL[curg], (float)crun);
    }
}

__launch_bounds__(256)
__global__ void k_node1(const __half* __restrict__ Ph, const int* __restrict__ cpos,
                        const int* __restrict__ dbase, const int* __restrict__ boff,
                        const int* __restrict__ dcnt, const float* __restrict__ f2,
                        const float* __restrict__ biasb, const int* __restrict__ batch,
                        float* __restrict__ hsum, float* __restrict__ gcnt) {
    int lane = threadIdx.x & 63;
    int wv = blockIdx.x * 4 + (threadIdx.x >> 6);
    int base = wv * 8;
    if (base >= 20000) return;
    int nn = 20000 - base; if (nn > 8) nn = 8;
    node_read_run(Ph, cpos, dbase, boff, dcnt, f2, batch, biasb[lane],
                  hsum, gcnt, base, nn, lane);
}

__launch_bounds__(256)
__global__ void k_node2(const __half* __restrict__ Ph, const int* __restrict__ cpos,
                        const int* __restrict__ dbase, const int* __restrict__ boff,
                        const int* __restrict__ dcnt, const float* __restrict__ f2,
                        P5f BiasB, P5i Batch, float* __restrict__ hsum, float* __restrict__ gcnt) {
    const int NB[4] = {0, 1250, 1875, 2188};  // ceil(N/8) prefix for l1..4
    int lane = threadIdx.x & 63;
    int wv = blockIdx.x * 4 + (threadIdx.x >> 6);
    if (wv >= 2345) return;
    int li = (wv >= 2188) ? 3 : (wv >= 1875) ? 2 : (wv >= 1250) ? 1 : 0;
    int l = li + 1;
    int base = (wv - NB[li]) * 8;
    int n = cN[l];
    if (base >= n) return;
    int nn = n - base; if (nn > 8) nn = 8;
    node_read_run(Ph + (size_t)(cSEOFF[l] - 324096) * 64, cpos + cEOFF[l],
                  dbase + cNOFF[l], boff + cNBLKOFF[l], dcnt + cNOFF[l],
                  f2 + (size_t)cNOFF[l] * 64, Batch.p[l], BiasB.p[l][lane],
                  hsum + l * 64, gcnt + l * 64, base, nn, lane);
}

// ---------------- FC + log_softmax: one block per graph ----------------
__global__ void fc_kernel(const float* __restrict__ hsum, const float* __restrict__ gcnt,
                          const float* __restrict__ fcw, const float* __restrict__ fcb,
                          float* __restrict__ out) {
    int g = blockIdx.x;
    int lane = threadIdx.x;  // 64
    float partial[10];
#pragma unroll
    for (int t = 0; t < 10; t++) partial[t] = 0.f;
#pragma unroll
    for (int k = 0; k < 5; k++) {
        int j = k * 64 + lane;
        float c = fmaxf(gcnt[k * 64 + g], 1.f);
        float h = hsum[g * 320 + j] / c;
        const float* fw = fcw + j * 10;
#pragma unroll
        for (int t = 0; t < 10; t++) partial[t] = fmaf(h, fw[t], partial[t]);
    }
#pragma unroll
    for (int off = 32; off >= 1; off >>= 1)
#pragma unroll
        for (int t = 0; t < 10; t++) partial[t] += __shfl_xor(partial[t], off, 64);
    if (lane == 0) {
        float logit[10];
#pragma unroll
        for (int t = 0; t < 10; t++) logit[t] = partial[t] + fcb[t];
        float m = logit[0];
#pragma unroll
        for (int t = 1; t < 10; t++) m = fmaxf(m, logit[t]);
        float sum = 0.f;
#pragma unroll
        for (int t = 0; t < 10; t++) sum += expf(logit[t] - m);
        float lse = m + logf(sum);
#pragma unroll
        for (int t = 0; t < 10; t++) out[g * 10 + t] = logit[t] - lse;
    }
}

extern "C" void kernel_launch(void* const* d_in, const int* in_sizes, int n_in,
                              void* d_out, int out_size, void* d_ws, size_t ws_size,
                              hipStream_t stream) {
    int* wsI = (int*)d_ws;
    int*   dcnt  = wsI;                          // 38750
    int*   rank  = dcnt + 38750;                 // 38750
    float* hsum  = (float*)(rank + 38750);       // 20480  (hsum[g*320 + l*64 + lane])
    float* gcnt  = hsum + 20480;                 // 320
    float* f2    = gcnt + 320;                   // 2,480,000 (R from rgemm)
    int*   dbase = (int*)(f2 + 2480000);         // 38750
    int*   bsum  = dbase + 38750;                // 160
    int*   boff  = bsum + 160;                   // 160
    int*   cpos  = boff + 160;                   // 620000
    int*   bb    = cpos + 620000;                // 155136
    int*   csPad = bb + 155136;                  // 320
    int*   cellTot = csPad + 320;                // 320
    int*   cot   = cellTot + 320;                // 10008
    int4*  cbrec = (int4*)(((size_t)(cot + 10008) + 15) & ~(size_t)15);   // 640512 recs
    int4*  darec = cbrec + 640512;               // 620000 recs
    ushortT* f1bf = (ushortT*)(darec + 620000);  // 1,840,000 ushorts
    uint4* whi   = (uint4*)(((size_t)(f1bf + 1840000) + 15) & ~(size_t)15);  // 288000
    uint4* rbsw  = whi + 288000;                 // 2304
    __half* Ph   = (__half*)(rbsw + 2304);       // 324096 rows of 64 (~41.5MB, reused)

    hipMemsetAsync(dcnt, 0, (size_t)(38750 * 2 + 20480 + 320) * sizeof(int), stream);

    P5f PS, X, WA, RootA, BiasA, WB, RootB, BiasB;
    P5i EI, Batch;
    for (int l = 0; l < 5; l++) {
        const int b = l * 10;
        X.p[l]     = (const float*)d_in[b + 0];
        PS.p[l]    = (const float*)d_in[b + 1];
        EI.p[l]    = (const int*)d_in[b + 2];
        Batch.p[l] = (const int*)d_in[b + 3];
        WA.p[l]    = (const float*)d_in[b + 4];
        RootA.p[l] = (const float*)d_in[b + 5];
        BiasA.p[l] = (const float*)d_in[b + 6];
        WB.p[l]    = (const float*)d_in[b + 7];
        RootB.p[l] = (const float*)d_in[b + 8];
        BiasB.p[l] = (const float*)d_in[b + 9];
    }

    // prep
    k_hist<<<2424, 256, 0, stream>>>(PS, EI, dcnt, bb);
    k_cellscan<<<5, 64, 0, stream>>>(bb, csPad, cellTot, cot);
    k_nscan1<<<154, 256, 0, stream>>>(dcnt, dbase, bsum);
    k_nscan2<<<5, 64, 0, stream>>>(bsum, boff);
    k_scatter<<<2424, 256, 0, stream>>>(PS, EI, bb, csPad, dbase, boff, rank,
                                        cbrec, darec, cpos);
    k_wswz<<<1134, 256, 0, stream>>>(WB, RootB, whi, rbsw);

    // conv A (all levels) -> f1bf
    conv_a_fused<<<2424, 256, 0, stream>>>(X, WA, RootA, BiasA, darec,
                                           dbase, boff, dcnt, f1bf);

    // R = f1 @ rootb into f2 (MFMA)
    k_rgemm<<<609, 256, 0, stream>>>(f1bf, rbsw, f2);

    // conv B (block-per-tile) + fused node-epilogue/readout; Ph reused l0 vs l1-4
    conv_b32<<<5064, 256, 0, stream>>>(f1bf, cbrec, whi, cot, csPad, cellTot, Ph);
    k_node1<<<625, 256, 0, stream>>>(Ph, cpos, dbase, boff, dcnt, f2, BiasB.p[0],
                                     Batch.p[0], hsum, gcnt);
    conv_b64<<<1236 + 3708, 256, 0, stream>>>(f1bf, cbrec, whi, cot, csPad, cellTot, Ph);
    k_node2<<<587, 256, 0, stream>>>(Ph, cpos, dbase, boff, dcnt, f2, BiasB, Batch,
                                     hsum, gcnt);

    // FC
    fc_kernel<<<64, 64, 0, stream>>>(hsum, gcnt, (const float*)d_in[50], (const float*)d_in[51],
                                     (float*)d_out);
}

// Round 13
// 475.748 us; speedup vs baseline: 1.1771x; 1.1265x over previous
//
#include <hip/hip_runtime.h>
#include <hip/hip_fp16.h>
#include <math.h>

#define NUM_GRAPHS 64

typedef unsigned short ushortT;
typedef __attribute__((ext_vector_type(8))) short bf16x8;
typedef __attribute__((ext_vector_type(4))) float f32x4;

// ---- static level tables ----
constexpr int cN[5]       = {20000, 10000, 5000, 2500, 1250};
constexpr int cE[5]       = {320000, 160000, 80000, 40000, 20000};
constexpr int cNOFF[6]    = {0, 20000, 30000, 35000, 37500, 38750};
constexpr int cEOFF[6]    = {0, 320000, 480000, 560000, 600000, 620000};
constexpr int cEBLKOFF[6] = {0, 1250, 1875, 2188, 2345, 2424};
constexpr int cNBLKOFF[6] = {0, 79, 119, 139, 149, 154};
constexpr int cMT[5]      = {5064, 2564, 1314, 689, 377};
constexpr int cTILEOFF[6] = {0, 5064, 7628, 8942, 9631, 10008};
constexpr int cSEOFF[6]   = {0, 324096, 488192, 572288, 616384, 640512};
constexpr int cF1OFF[6]   = {0, 640000, 1280000, 1600000, 1760000, 1840000};
constexpr int cWOFF[6]    = {0, 32000, 96000, 160000, 224000, 288000};
constexpr int cABLK[6]    = {0, 1250, 1875, 2188, 2345, 2424};   // ceil(N/16) prefix
constexpr int cRBOFF[5]   = {0, 256, 768, 1280, 1792};           // rootb swizzle uint4 offsets
constexpr int cRGB[6]     = {0, 313, 470, 549, 589, 609};        // ceil(N/64) prefix

struct P5f { const float* p[5]; };
struct P5i { const int* p[5]; };

__device__ __forceinline__ int lvl_e(int b) {
    return (b >= cEBLKOFF[4]) ? 4 : (b >= cEBLKOFF[3]) ? 3 : (b >= cEBLKOFF[2]) ? 2 : (b >= cEBLKOFF[1]) ? 1 : 0;
}
__device__ __forceinline__ int lvl_n(int b) {
    return (b >= cNBLKOFF[4]) ? 4 : (b >= cNBLKOFF[3]) ? 3 : (b >= cNBLKOFF[2]) ? 2 : (b >= cNBLKOFF[1]) ? 1 : 0;
}

__device__ __forceinline__ ushortT f2bf(float f) {
    union { float f; unsigned int u; } v; v.f = f;
    unsigned int r = (v.u + 0x7FFFu + ((v.u >> 16) & 1u)) >> 16;
    return (ushortT)r;
}
__device__ __forceinline__ float h2f_lo(unsigned int u) {
    return __half2float(__ushort_as_half((ushortT)(u & 0xFFFFu)));
}
__device__ __forceinline__ float h2f_hi(unsigned int u) {
    return __half2float(__ushort_as_half((ushortT)(u >> 16)));
}

// ---------------- prep: per-block cell histogram + dst degree count ----------------
__global__ void k_hist(P5f PS, P5i EI, int* __restrict__ dcnt, int* __restrict__ bb) {
    int b = blockIdx.x;
    int l = lvl_e(b);
    int lb = b - cEBLKOFF[l];
    int E = cE[l];
    __shared__ int h[64];
    int t = threadIdx.x;
    if (t < 64) h[t] = 0;
    __syncthreads();
    int e = lb * 256 + t;
    if (e < E) {
        atomicAdd(&dcnt[cNOFF[l] + EI.p[l][E + e]], 1);
        const float* ps = PS.p[l];
        int c = (int)floorf(ps[e * 3] * 4.f) * 16 + (int)floorf(ps[e * 3 + 1] * 4.f) * 4
              + (int)floorf(ps[e * 3 + 2] * 4.f);
        atomicAdd(&h[c], 1);
    }
    __syncthreads();
    if (t < 64) bb[(size_t)b * 64 + t] = h[t];
}

// ---------------- cell scan ----------------
__global__ void k_cellscan(int* __restrict__ bb_all, int* __restrict__ csPad,
                           int* __restrict__ cellTot, int* __restrict__ cot_all) {
    int l = blockIdx.x;
    int c = threadIdx.x;
    int* bb = bb_all + (size_t)cEBLKOFF[l] * 64;
    int nblk = cEBLKOFF[l + 1] - cEBLKOFF[l];
    int run = 0;
    int b = 0;
    for (; b + 16 <= nblk; b += 16) {
        int v[16];
#pragma unroll
        for (int u = 0; u < 16; u++) v[u] = bb[(b + u) * 64 + c];
#pragma unroll
        for (int u = 0; u < 16; u++) { bb[(b + u) * 64 + c] = run; run += v[u]; }
    }
    for (; b < nblk; b++) { int v = bb[b * 64 + c]; bb[b * 64 + c] = run; run += v; }
    int tot = run;
    cellTot[l * 64 + c] = tot;
    int tiles = (tot + 63) >> 6;
    int x = tiles;
#pragma unroll
    for (int off = 1; off < 64; off <<= 1) { int y = __shfl_up(x, off, 64); if (c >= off) x += y; }
    int tileBase = x - tiles;
    csPad[l * 64 + c] = tileBase * 64;
    int* cot = cot_all + cTILEOFF[l];
    for (int i = 0; i < tiles; i++) cot[tileBase + i] = c;
    int nT = __shfl(x, 63, 64);
    int mt = cMT[l];
    for (int i = nT + c; i < mt; i += 64) cot[i] = -1;
}

// ---------------- node-degree scans ----------------
__global__ void k_nscan1(const int* __restrict__ dcnt, int* __restrict__ dbase, int* __restrict__ bsum) {
    int b = blockIdx.x;
    int l = lvl_n(b);
    int lb = b - cNBLKOFF[l];
    int n = cN[l];
    __shared__ int sh[256];
    int t = threadIdx.x;
    int i = lb * 256 + t;
    int v = (i < n) ? dcnt[cNOFF[l] + i] : 0;
    sh[t] = v;
    __syncthreads();
    for (int off = 1; off < 256; off <<= 1) {
        int y = (t >= off) ? sh[t - off] : 0;
        __syncthreads();
        sh[t] += y;
        __syncthreads();
    }
    if (i < n) dbase[cNOFF[l] + i] = sh[t] - v;
    if (t == 255) bsum[b] = sh[255];
}

__global__ void k_nscan2(const int* __restrict__ bsum, int* __restrict__ boff) {
    int l = blockIdx.x;
    int o = cNBLKOFF[l];
    int nb = cNBLKOFF[l + 1] - o;
    int t = threadIdx.x;
    int v = (t < nb) ? bsum[o + t] : 0;
    int s = v;
#pragma unroll
    for (int off = 1; off < 64; off <<= 1) { int y = __shfl_up(s, off, 64); if (t >= off) s += y; }
    int tot = __shfl(s, 63, 64);
    if (t < nb) boff[o + t] = s - v;
    int t2 = t + 64;
    int v2 = (t2 < nb) ? bsum[o + t2] : 0;
    int s2 = v2;
#pragma unroll
    for (int off = 1; off < 64; off <<= 1) { int y = __shfl_up(s2, off, 64); if (t >= off) s2 += y; }
    if (t2 < nb) boff[o + t2] = tot + s2 - v2;
}

// ---- merged scatter: one edge pass -> cbrec (cell order), darec (dst order), cpos ----
__global__ void k_scatter(P5f PS, P5i EI, const int* __restrict__ bb, const int* __restrict__ csPad,
                          const int* __restrict__ dbase, const int* __restrict__ boff,
                          int* __restrict__ rank,
                          int4* __restrict__ cbrec, int4* __restrict__ darec,
                          int* __restrict__ cpos) {
    int b = blockIdx.x;
    int l = lvl_e(b);
    int lb = b - cEBLKOFF[l];
    int E = cE[l];
    __shared__ int base[64];
    __shared__ int cnt[64];
    int t = threadIdx.x;
    if (t < 64) { base[t] = bb[(size_t)b * 64 + t] + csPad[l * 64 + t]; cnt[t] = 0; }
    __syncthreads();
    int e = lb * 256 + t;
    if (e >= E) return;
    const float* ps = PS.p[l];
    float v0 = ps[e * 3] * 4.f, v1 = ps[e * 3 + 1] * 4.f, v2 = ps[e * 3 + 2] * 4.f;
    float f0 = floorf(v0), f1v = floorf(v1), f2v = floorf(v2);
    int c = (int)f0 * 16 + (int)f1v * 4 + (int)f2v;
    int r = atomicAdd(&cnt[c], 1);
    int posc = base[c] + r;
    const int* ei = EI.p[l];
    int src = ei[e];
    int dst = ei[E + e];
    int posd = dbase[cNOFF[l] + dst] + boff[cNBLKOFF[l] + (dst >> 8)]
             + atomicAdd(&rank[cNOFF[l] + dst], 1);
    unsigned int fxfy = (unsigned int)__half_as_ushort(__float2half(v0 - f0))
                      | ((unsigned int)__half_as_ushort(__float2half(v1 - f1v)) << 16);
    unsigned int fzp  = (unsigned int)__half_as_ushort(__float2half(v2 - f2v));
    int4 rc;
    rc.x = src; rc.y = 0; rc.z = (int)fxfy; rc.w = (int)fzp;
    cbrec[cSEOFF[l] + posc] = rc;
    int4 rd;
    rd.x = src | (dst << 16); rd.y = c; rd.z = (int)fxfy; rd.w = (int)fzp;
    darec[cEOFF[l] + posd] = rd;
    cpos[cEOFF[l] + posd] = posc;
}

// -------- W + rootb swizzle (fused): fp32 -> MFMA B-frag bf16 ----------
__global__ void k_wswz(P5f WB, P5f RootB, uint4* __restrict__ hi4, uint4* __restrict__ rb) {
    int idx = blockIdx.x * 256 + threadIdx.x;
    if (idx >= 290304) return;
    if (idx < 288000) {
        int l = (idx >= 224000) ? 4 : (idx >= 160000) ? 3 : (idx >= 96000) ? 2 : (idx >= 32000) ? 1 : 0;
        int local = idx - cWOFF[l];
        int T = l ? 2 : 1, C = l ? 64 : 32;
        int lane = local & 63;
        int blk = (local >> 6) & 3;
        int rest = local >> 8;
        int st = rest % T, s = rest / T;
        int q = lane >> 4, n = blk * 16 + (lane & 15);
        const float* W = WB.p[l];
        union { ushortT u[8]; uint4 v; } ph;
#pragma unroll
        for (int j = 0; j < 8; j++) {
            int k = st * 32 + q * 8 + j;
            ph.u[j] = f2bf(W[((size_t)s * C + k) * 64 + n]);
        }
        hi4[idx] = ph.v;
    } else {
        int id2 = idx - 288000;
        int l = (id2 >= 1792) ? 4 : (id2 >= 1280) ? 3 : (id2 >= 768) ? 2 : (id2 >= 256) ? 1 : 0;
        int local = id2 - cRBOFF[l];
        int lane = local & 63;
        int w = (local >> 6) & 3;
        int st = local >> 8;
        int q = lane >> 4, n = w * 16 + (lane & 15);
        const float* R = RootB.p[l];
        union { ushortT u[8]; uint4 v; } ph;
#pragma unroll
        for (int j = 0; j < 8; j++) {
            int k = st * 32 + q * 8 + j;
            ph.u[j] = f2bf(R[k * 64 + n]);
        }
        rb[id2] = ph.v;
    }
}

// ---- Fused Conv A: LDS-staged edges, corner-parallel, ILP'd S@Wa tail ---------------
template<int C1>
__device__ __forceinline__ void conv_a_gemm(const float* __restrict__ S, const float* __restrict__ Wa,
                                            const float* __restrict__ x, const float* __restrict__ ra,
                                            const float* __restrict__ ba, const int* __restrict__ dcl,
                                            int node0, int nn, ushortT* __restrict__ f1bfl, int t) {
    int ch = t % C1;
    int npp = 256 / C1;
    float bias = ba[ch];
    float root = ra[ch];
    for (int node = t / C1; node < nn; node += npp) {
        const float* Sr = S + node * 126;
        float s0 = 0.f, s1 = 0.f, s2 = 0.f, s3 = 0.f;
#pragma unroll
        for (int k = 0; k < 124; k += 4) {
            s0 = fmaf(Sr[k],     Wa[k * C1 + ch],       s0);
            s1 = fmaf(Sr[k + 1], Wa[(k + 1) * C1 + ch], s1);
            s2 = fmaf(Sr[k + 2], Wa[(k + 2) * C1 + ch], s2);
            s3 = fmaf(Sr[k + 3], Wa[(k + 3) * C1 + ch], s3);
        }
        float s = ((s0 + s1) + (s2 + s3)) + Sr[124] * Wa[124 * C1 + ch];
        int gnode = node0 + node;
        int dv = dcl[gnode];
        float d = (float)(dv > 1 ? dv : 1);
        float o = s / d + x[gnode] * root + bias;
        f1bfl[(size_t)gnode * C1 + ch] = f2bf(fmaxf(o, 0.f));
    }
}

__launch_bounds__(256)
__global__ void conv_a_fused(P5f X, P5f WA, P5f RootA, P5f BiasA,
                             const int4* __restrict__ darec,
                             const int* __restrict__ dbase, const int* __restrict__ boff,
                             const int* __restrict__ dcnt, ushortT* __restrict__ f1bf) {
    __shared__ float S[16 * 126];
    __shared__ int infoS[256];
    __shared__ unsigned int fxyS[256];
    __shared__ unsigned int fzS[256];
    __shared__ float xsS[256];
    int b = blockIdx.x;
    int l = (b >= cABLK[4]) ? 4 : (b >= cABLK[3]) ? 3 : (b >= cABLK[2]) ? 2 : (b >= cABLK[1]) ? 1 : 0;
    int node0 = (b - cABLK[l]) * 16;
    int n = cN[l];
    int nn = n - node0; if (nn > 16) nn = 16;
    int t = threadIdx.x;
    for (int i = t; i < 16 * 126; i += 256) S[i] = 0.f;
    const int* db = dbase + cNOFF[l];
    const int* bo = boff + cNBLKOFF[l];
    int estart = db[node0] + bo[node0 >> 8];
    int vend = node0 + nn;
    int eend = (vend >= n) ? cE[l] : (db[vend] + bo[vend >> 8]);
    const float* x = X.p[l];
    const int4* dr = darec + cEOFF[l];
    const int bx = t & 1, by = (t >> 1) & 1, bz = (t >> 2) & 1;
    for (int cs = estart; cs < eend; cs += 256) {
        int p = cs + t;
        if (p < eend) {
            int4 r = dr[p];
            infoS[t] = ((((unsigned int)r.x) >> 16) - node0) * 64 + r.y;
            fxyS[t] = (unsigned int)r.z;
            fzS[t] = (unsigned int)r.w;
            xsS[t] = x[r.x & 0xFFFF];
        }
        __syncthreads();
        int ne = eend - cs; if (ne > 256) ne = 256;
        for (int j = (t >> 3); j < ne; j += 32) {
            int info = infoS[j];
            int nl = info >> 6, cell = info & 63;
            unsigned int uz = fxyS[j];
            float fx = h2f_lo(uz), fy = h2f_hi(uz), fz = h2f_lo(fzS[j]);
            float xs = xsS[j];
            int cx = cell >> 4, cy = (cell >> 2) & 3, cz = cell & 3;
            int slot = (cx + bx) * 25 + (cy + by) * 5 + (cz + bz);
            float wc = (bx ? fx : 1.f - fx) * (by ? fy : 1.f - fy) * (bz ? fz : 1.f - fz);
            atomicAdd(&S[nl * 126 + slot], wc * xs);
        }
        __syncthreads();
    }
    if (l == 0)
        conv_a_gemm<32>(S, WA.p[0], X.p[0], RootA.p[0], BiasA.p[0], dcnt + cNOFF[0],
                        node0, nn, f1bf + cF1OFF[0], t);
    else
        conv_a_gemm<64>(S, WA.p[l], X.p[l], RootA.p[l], BiasA.p[l], dcnt + cNOFF[l],
                        node0, nn, f1bf + cF1OFF[l], t);
}

// ---- R-gemm: f2 = f1bf @ rootb (bf16 MFMA), per-64-node tiles -----------------------
__launch_bounds__(256)
__global__ void k_rgemm(const ushortT* __restrict__ f1bf, const uint4* __restrict__ rb,
                        float* __restrict__ f2) {
    int b = blockIdx.x;
    int l = (b >= cRGB[4]) ? 4 : (b >= cRGB[3]) ? 3 : (b >= cRGB[2]) ? 2 : (b >= cRGB[1]) ? 1 : 0;
    int node0 = (b - cRGB[l]) * 64;
    int n = cN[l];
    int nn = n - node0; if (nn > 64) nn = 64;
    int t = threadIdx.x;
    int lane = t & 63, w = t >> 6;
    int q = lane >> 4, m = lane & 15;
    const int CIN = l ? 64 : 32;
    const int T = l ? 2 : 1;
    const ushortT* fl = f1bf + cF1OFF[l];
    const uint4* rbl = rb + cRBOFF[l];
    f32x4 C[4];
#pragma unroll
    for (int mt = 0; mt < 4; mt++) C[mt] = (f32x4){0.f, 0.f, 0.f, 0.f};
    for (int st = 0; st < T; st++) {
        bf16x8 bh = __builtin_bit_cast(bf16x8, rbl[(st * 4 + w) * 64 + lane]);
#pragma unroll
        for (int mt = 0; mt < 4; mt++) {
            int row = 16 * mt + m;
            int nr = node0 + row; if (nr > n - 1) nr = n - 1;
            bf16x8 a = *(const bf16x8*)&fl[(size_t)nr * CIN + st * 32 + q * 8];
            C[mt] = __builtin_amdgcn_mfma_f32_16x16x32_bf16(a, bh, C[mt], 0, 0, 0);
        }
    }
#pragma unroll
    for (int mt = 0; mt < 4; mt++)
#pragma unroll
        for (int rr = 0; rr < 4; rr++) {
            int row = 16 * mt + q * 4 + rr;
            if (row < nn)
                f2[(size_t)(cNOFF[l] + node0 + row) * 64 + 16 * w + m] = C[mt][rr];
        }
}

// ---- Conv B tile: block-per-tile (4 waves share tile), z-paired epilogue ------------
template<int CIN>
__device__ __forceinline__ void conv_b_tile(
    const ushortT* __restrict__ f1bfl, const int4* __restrict__ cbrec_l,
    const uint4* __restrict__ whiL,
    int cell, int tb, int valid, __half* __restrict__ pout,
    float* fxs, float* fys, float* fzs, int* srcs) {
    const int T = CIN / 32;
    int t = threadIdx.x;
    if (t < 64) {
        bool v = t < valid;
        int4 r;
        if (v) r = cbrec_l[tb + t]; else { r.x = 0; r.y = 0; r.z = 0; r.w = 0; }
        srcs[t] = r.x;
        unsigned int uz = (unsigned int)r.z;
        fxs[t] = h2f_lo(uz);
        fys[t] = h2f_hi(uz);
        fzs[t] = h2f_lo((unsigned int)r.w);
    }
    __syncthreads();

    int lane = t & 63, w = t >> 6;
    int q = lane >> 4, m = lane & 15;

    bf16x8 ahr[4][T];
#pragma unroll
    for (int mt = 0; mt < 4; mt++) {
        int src = srcs[16 * mt + m];
#pragma unroll
        for (int st = 0; st < T; st++)
            ahr[mt][st] = *(const bf16x8*)&f1bfl[(size_t)src * CIN + st * 32 + q * 8];
    }
    float fxr[16], fyr[16], fzr[16], gzr[16];
#pragma unroll
    for (int mt = 0; mt < 4; mt++)
#pragma unroll
        for (int rr = 0; rr < 4; rr++) {
            int row = 16 * mt + q * 4 + rr;
            fxr[mt * 4 + rr] = fxs[row];
            fyr[mt * 4 + rr] = fys[row];
            float fz = fzs[row];
            fzr[mt * 4 + rr] = fz;
            gzr[mt * 4 + rr] = 1.f - fz;
        }
    int cx = cell >> 4, cy = (cell >> 2) & 3, cz = cell & 3;
    f32x4 acc[4];
#pragma unroll
    for (int mt = 0; mt < 4; mt++) acc[mt] = (f32x4){0.f, 0.f, 0.f, 0.f};

#pragma unroll
    for (int xy = 0; xy < 4; xy++) {
        const int bx = xy & 1, by = xy >> 1;
        int slot0 = (cx + bx) * 25 + (cy + by) * 5 + cz;  // bz=0; bz=1 is slot0+1
        f32x4 C0[4], C1[4];
#pragma unroll
        for (int mt = 0; mt < 4; mt++) {
            C0[mt] = (f32x4){0.f, 0.f, 0.f, 0.f};
            C1[mt] = (f32x4){0.f, 0.f, 0.f, 0.f};
        }
#pragma unroll
        for (int st = 0; st < T; st++) {
            bf16x8 b0 = __builtin_bit_cast(bf16x8, whiL[((size_t)(slot0 * T + st) * 4 + w) * 64 + lane]);
            bf16x8 b1 = __builtin_bit_cast(bf16x8, whiL[((size_t)((slot0 + 1) * T + st) * 4 + w) * 64 + lane]);
#pragma unroll
            for (int mt = 0; mt < 4; mt++) {
                C0[mt] = __builtin_amdgcn_mfma_f32_16x16x32_bf16(ahr[mt][st], b0, C0[mt], 0, 0, 0);
                C1[mt] = __builtin_amdgcn_mfma_f32_16x16x32_bf16(ahr[mt][st], b1, C1[mt], 0, 0, 0);
            }
        }
#pragma unroll
        for (int mt = 0; mt < 4; mt++)
#pragma unroll
            for (int rr = 0; rr < 4; rr++) {
                int i16 = mt * 4 + rr;
                float wxy = (bx ? fxr[i16] : 1.f - fxr[i16]) * (by ? fyr[i16] : 1.f - fyr[i16]);
                float tt = fmaf(fzr[i16], C1[mt][rr], gzr[i16] * C0[mt][rr]);
                acc[mt][rr] = fmaf(wxy, tt, acc[mt][rr]);
            }
    }
    // coalesced cell-order store
#pragma unroll
    for (int mt = 0; mt < 4; mt++)
#pragma unroll
        for (int rr = 0; rr < 4; rr++) {
            int row = 16 * mt + q * 4 + rr;
            pout[(size_t)(tb + row) * 64 + 16 * w + m] = __float2half(acc[mt][rr]);
        }
}

// ---- merged conv B: all 10008 tiles (l0 + l1-4), disjoint Ph regions ----------------
__launch_bounds__(256)
__global__ void conv_b_all(const ushortT* __restrict__ f1bf, const int4* __restrict__ cbrec,
                           const uint4* __restrict__ whi,
                           const int* __restrict__ cot, const int* __restrict__ csPad,
                           const int* __restrict__ cellTot, __half* __restrict__ Ph) {
    __shared__ float fxs[64], fys[64], fzs[64];
    __shared__ int srcs[64];
    int blk = blockIdx.x;
    if (blk < 5064) {
        int cell = cot[blk];
        if (cell < 0) return;
        int tb = blk * 64;
        int valid = csPad[cell] + cellTot[cell] - tb;
        if (valid > 64) valid = 64;
        conv_b_tile<32>(f1bf, cbrec, whi, cell, tb, valid, Ph, fxs, fys, fzs, srcs);
    } else {
        const int TB2[4] = {0, 2564, 3878, 4567};
        int b2 = blk - 5064;
        int li = (b2 >= 4567) ? 3 : (b2 >= 3878) ? 2 : (b2 >= 2564) ? 1 : 0;
        int l = li + 1;
        int tile = b2 - TB2[li];
        int cell = cot[cTILEOFF[l] + tile];
        if (cell < 0) return;
        int tb = tile * 64;
        int valid = csPad[l * 64 + cell] + cellTot[l * 64 + cell] - tb;
        if (valid > 64) valid = 64;
        conv_b_tile<64>(f1bf + cF1OFF[l], cbrec + cSEOFF[l], whi + cWOFF[l],
                        cell, tb, valid, Ph + (size_t)cSEOFF[l] * 64,
                        fxs, fys, fzs, srcs);
    }
}

// ---- merged node epilogue: one node per wave; gather Ph + R + bias + relu -> f2 -----
__launch_bounds__(256)
__global__ void node_b_all(const __half* __restrict__ Ph, const int* __restrict__ cpos,
                           const int* __restrict__ dbase, const int* __restrict__ boff,
                           const int* __restrict__ dcnt, P5f BiasB, float* __restrict__ f2) {
    int lane = threadIdx.x & 63;
    int blk = blockIdx.x;
    int l, node;
    if (blk < 5000) {
        l = 0;
        node = blk * 4 + (threadIdx.x >> 6);
        if (node >= 20000) return;
    } else {
        const int NB2[4] = {0, 2500, 3750, 4375};
        int b2 = blk - 5000;
        int li = (b2 >= 4375) ? 3 : (b2 >= 3750) ? 2 : (b2 >= 2500) ? 1 : 0;
        l = li + 1;
        node = (b2 - NB2[li]) * 4 + (threadIdx.x >> 6);
        if (node >= cN[l]) return;
    }
    int start = dbase[cNOFF[l] + node] + boff[cNBLKOFF[l] + (node >> 8)];
    int deg = dcnt[cNOFF[l] + node];
    const __half* PhL = Ph + (size_t)cSEOFF[l] * 64;
    const int* cposL = cpos + cEOFF[l];
    float* f2row = f2 + (size_t)(cNOFF[l] + node) * 64;
    float s0 = 0.f, s1 = 0.f;
    int k = 0;
    for (; k + 2 <= deg; k += 2) {
        int r0 = cposL[start + k];
        int r1 = cposL[start + k + 1];
        s0 += __half2float(PhL[(size_t)r0 * 64 + lane]);
        s1 += __half2float(PhL[(size_t)r1 * 64 + lane]);
    }
    if (k < deg) s0 += __half2float(PhL[(size_t)cposL[start + k] * 64 + lane]);
    float s = (s0 + s1) / (float)(deg > 1 ? deg : 1)
            + f2row[lane] + BiasB.p[l][lane];
    f2row[lane] = fmaxf(s, 0.f);
}

// ---------------- readout: run-accumulated graph mean sums ----------------
__launch_bounds__(256)
__global__ void k_read(const float* __restrict__ f2, P5i Batch,
                       float* __restrict__ hsum, float* __restrict__ gcnt) {
    const int RC[5] = {0, 1250, 1875, 2188, 2345};
    int t = threadIdx.x;
    int lane = t & 63;
    int w = blockIdx.x * 4 + (t >> 6);
    if (w >= 2424) return;
    int l = (w >= 2345) ? 4 : (w >= 2188) ? 3 : (w >= 1875) ? 2 : (w >= 1250) ? 1 : 0;
    int base = (w - RC[l]) * 16;
    int Nl = cN[l];
    int nn = Nl - base; if (nn > 16) nn = 16;
    const int* batch = Batch.p[l];
    const float* fb = f2 + (size_t)(cNOFF[l] + base) * 64;
    int curg = -1; float hacc = 0.f; int crun = 0;
    for (int j = 0; j < nn; j++) {
        int g = batch[base + j];
        if (g != curg) {
            if (curg >= 0) {
                atomicAdd(&hsum[curg * 320 + l * 64 + lane], hacc);
                if (lane == 0) atomicAdd(&gcnt[l * 64 + curg], (float)crun);
            }
            curg = g; hacc = 0.f; crun = 0;
        }
        hacc += fb[(size_t)j * 64 + lane];
        crun++;
    }
    if (curg >= 0) {
        atomicAdd(&hsum[curg * 320 + l * 64 + lane], hacc);
        if (lane == 0) atomicAdd(&gcnt[l * 64 + curg], (float)crun);
    }
}

// ---------------- FC + log_softmax: one block per graph ----------------
__global__ void fc_kernel(const float* __restrict__ hsum, const float* __restrict__ gcnt,
                          const float* __restrict__ fcw, const float* __restrict__ fcb,
                          float* __restrict__ out) {
    int g = blockIdx.x;
    int lane = threadIdx.x;  // 64
    float partial[10];
#pragma unroll
    for (int t = 0; t < 10; t++) partial[t] = 0.f;
#pragma unroll
    for (int k = 0; k < 5; k++) {
        int j = k * 64 + lane;
        float c = fmaxf(gcnt[k * 64 + g], 1.f);
        float h = hsum[g * 320 + j] / c;
        const float* fw = fcw + j * 10;
#pragma unroll
        for (int t = 0; t < 10; t++) partial[t] = fmaf(h, fw[t], partial[t]);
    }
#pragma unroll
    for (int off = 32; off >= 1; off >>= 1)
#pragma unroll
        for (int t = 0; t < 10; t++) partial[t] += __shfl_xor(partial[t], off, 64);
    if (lane == 0) {
        float logit[10];
#pragma unroll
        for (int t = 0; t < 10; t++) logit[t] = partial[t] + fcb[t];
        float m = logit[0];
#pragma unroll
        for (int t = 1; t < 10; t++) m = fmaxf(m, logit[t]);
        float sum = 0.f;
#pragma unroll
        for (int t = 0; t < 10; t++) sum += expf(logit[t] - m);
        float lse = m + logf(sum);
#pragma unroll
        for (int t = 0; t < 10; t++) out[g * 10 + t] = logit[t] - lse;
    }
}

extern "C" void kernel_launch(void* const* d_in, const int* in_sizes, int n_in,
                              void* d_out, int out_size, void* d_ws, size_t ws_size,
                              hipStream_t stream) {
    int* wsI = (int*)d_ws;
    int*   dcnt  = wsI;                          // 38750
    int*   rank  = dcnt + 38750;                 // 38750
    float* hsum  = (float*)(rank + 38750);       // 20480  (hsum[g*320 + l*64 + lane])
    float* gcnt  = hsum + 20480;                 // 320
    float* f2    = gcnt + 320;                   // 2,480,000 (R from rgemm)
    int*   dbase = (int*)(f2 + 2480000);         // 38750
    int*   bsum  = dbase + 38750;                // 160
    int*   boff  = bsum + 160;                   // 160
    int*   cpos  = boff + 160;                   // 620000
    int*   bb    = cpos + 620000;                // 155136
    int*   csPad = bb + 155136;                  // 320
    int*   cellTot = csPad + 320;                // 320
    int*   cot   = cellTot + 320;                // 10008
    int4*  cbrec = (int4*)(((size_t)(cot + 10008) + 15) & ~(size_t)15);   // 640512 recs
    int4*  darec = cbrec + 640512;               // 620000 recs
    ushortT* f1bf = (ushortT*)(darec + 620000);  // 1,840,000 ushorts
    uint4* whi   = (uint4*)(((size_t)(f1bf + 1840000) + 15) & ~(size_t)15);  // 288000
    uint4* rbsw  = whi + 288000;                 // 2304
    __half* Ph   = (__half*)(rbsw + 2304);       // 640512 rows of 64 (~82MB, DISJOINT per level)

    hipMemsetAsync(dcnt, 0, (size_t)(38750 * 2 + 20480 + 320) * sizeof(int), stream);

    P5f PS, X, WA, RootA, BiasA, WB, RootB, BiasB;
    P5i EI, Batch;
    for (int l = 0; l < 5; l++) {
        const int b = l * 10;
        X.p[l]     = (const float*)d_in[b + 0];
        PS.p[l]    = (const float*)d_in[b + 1];
        EI.p[l]    = (const int*)d_in[b + 2];
        Batch.p[l] = (const int*)d_in[b + 3];
        WA.p[l]    = (const float*)d_in[b + 4];
        RootA.p[l] = (const float*)d_in[b + 5];
        BiasA.p[l] = (const float*)d_in[b + 6];
        WB.p[l]    = (const float*)d_in[b + 7];
        RootB.p[l] = (const float*)d_in[b + 8];
        BiasB.p[l] = (const float*)d_in[b + 9];
    }

    // prep
    k_hist<<<2424, 256, 0, stream>>>(PS, EI, dcnt, bb);
    k_cellscan<<<5, 64, 0, stream>>>(bb, csPad, cellTot, cot);
    k_nscan1<<<154, 256, 0, stream>>>(dcnt, dbase, bsum);
    k_nscan2<<<5, 64, 0, stream>>>(bsum, boff);
    k_scatter<<<2424, 256, 0, stream>>>(PS, EI, bb, csPad, dbase, boff, rank,
                                        cbrec, darec, cpos);
    k_wswz<<<1134, 256, 0, stream>>>(WB, RootB, whi, rbsw);

    // conv A (all levels) -> f1bf
    conv_a_fused<<<2424, 256, 0, stream>>>(X, WA, RootA, BiasA, darec,
                                           dbase, boff, dcnt, f1bf);

    // R = f1 @ rootb into f2 (MFMA)
    k_rgemm<<<609, 256, 0, stream>>>(f1bf, rbsw, f2);

    // conv B (ALL levels, one dispatch) -> Ph; node epilogue (ALL levels) -> f2
    conv_b_all<<<10008, 256, 0, stream>>>(f1bf, cbrec, whi, cot, csPad, cellTot, Ph);
    node_b_all<<<9688, 256, 0, stream>>>(Ph, cpos, dbase, boff, dcnt, BiasB, f2);

    // readout + FC
    k_read<<<606, 256, 0, stream>>>(f2, Batch, hsum, gcnt);
    fc_kernel<<<64, 64, 0, stream>>>(hsum, gcnt, (const float*)d_in[50], (const float*)d_in[51],
                                     (float*)d_out);
}

// Round 14
// 473.268 us; speedup vs baseline: 1.1832x; 1.0052x over previous
//
#include <hip/hip_runtime.h>
#include <hip/hip_fp16.h>
#include <math.h>

#define NUM_GRAPHS 64

typedef unsigned short ushortT;
typedef __attribute__((ext_vector_type(8))) short bf16x8;
typedef __attribute__((ext_vector_type(4))) float f32x4;

// ---- static level tables ----
constexpr int cN[5]       = {20000, 10000, 5000, 2500, 1250};
constexpr int cE[5]       = {320000, 160000, 80000, 40000, 20000};
constexpr int cNOFF[6]    = {0, 20000, 30000, 35000, 37500, 38750};
constexpr int cEOFF[6]    = {0, 320000, 480000, 560000, 600000, 620000};
constexpr int cEBLKOFF[6] = {0, 1250, 1875, 2188, 2345, 2424};
constexpr int cNBLKOFF[6] = {0, 79, 119, 139, 149, 154};
constexpr int cMT[5]      = {5064, 2564, 1314, 689, 377};
constexpr int cTILEOFF[6] = {0, 5064, 7628, 8942, 9631, 10008};
constexpr int cSEOFF[6]   = {0, 324096, 488192, 572288, 616384, 640512};
constexpr int cF1OFF[6]   = {0, 640000, 1280000, 1600000, 1760000, 1840000};
constexpr int cWOFF[6]    = {0, 32000, 96000, 160000, 224000, 288000};
constexpr int cABLK[6]    = {0, 1250, 1875, 2188, 2345, 2424};   // ceil(N/16) prefix
constexpr int cRBOFF[5]   = {0, 256, 768, 1280, 1792};           // rootb swizzle uint4 offsets
constexpr int cRGB[6]     = {0, 313, 470, 549, 589, 609};        // ceil(N/64) prefix

struct P5f { const float* p[5]; };
struct P5i { const int* p[5]; };

__device__ __forceinline__ int lvl_e(int b) {
    return (b >= cEBLKOFF[4]) ? 4 : (b >= cEBLKOFF[3]) ? 3 : (b >= cEBLKOFF[2]) ? 2 : (b >= cEBLKOFF[1]) ? 1 : 0;
}
__device__ __forceinline__ int lvl_n(int b) {
    return (b >= cNBLKOFF[4]) ? 4 : (b >= cNBLKOFF[3]) ? 3 : (b >= cNBLKOFF[2]) ? 2 : (b >= cNBLKOFF[1]) ? 1 : 0;
}

__device__ __forceinline__ ushortT f2bf(float f) {
    union { float f; unsigned int u; } v; v.f = f;
    unsigned int r = (v.u + 0x7FFFu + ((v.u >> 16) & 1u)) >> 16;
    return (ushortT)r;
}
__device__ __forceinline__ float h2f_lo(unsigned int u) {
    return __half2float(__ushort_as_half((ushortT)(u & 0xFFFFu)));
}
__device__ __forceinline__ float h2f_hi(unsigned int u) {
    return __half2float(__ushort_as_half((ushortT)(u >> 16)));
}

// ---------------- prep: per-block cell histogram + dst degree count ----------------
__global__ void k_hist(P5f PS, P5i EI, int* __restrict__ dcnt, int* __restrict__ bb) {
    int b = blockIdx.x;
    int l = lvl_e(b);
    int lb = b - cEBLKOFF[l];
    int E = cE[l];
    __shared__ int h[64];
    int t = threadIdx.x;
    if (t < 64) h[t] = 0;
    __syncthreads();
    int e = lb * 256 + t;
    if (e < E) {
        atomicAdd(&dcnt[cNOFF[l] + EI.p[l][E + e]], 1);
        const float* ps = PS.p[l];
        int c = (int)floorf(ps[e * 3] * 4.f) * 16 + (int)floorf(ps[e * 3 + 1] * 4.f) * 4
              + (int)floorf(ps[e * 3 + 2] * 4.f);
        atomicAdd(&h[c], 1);
    }
    __syncthreads();
    if (t < 64) bb[(size_t)b * 64 + t] = h[t];
}

// ---------------- cell scan ----------------
__global__ void k_cellscan(int* __restrict__ bb_all, int* __restrict__ csPad,
                           int* __restrict__ cellTot, int* __restrict__ cot_all) {
    int l = blockIdx.x;
    int c = threadIdx.x;
    int* bb = bb_all + (size_t)cEBLKOFF[l] * 64;
    int nblk = cEBLKOFF[l + 1] - cEBLKOFF[l];
    int run = 0;
    int b = 0;
    for (; b + 16 <= nblk; b += 16) {
        int v[16];
#pragma unroll
        for (int u = 0; u < 16; u++) v[u] = bb[(b + u) * 64 + c];
#pragma unroll
        for (int u = 0; u < 16; u++) { bb[(b + u) * 64 + c] = run; run += v[u]; }
    }
    for (; b < nblk; b++) { int v = bb[b * 64 + c]; bb[b * 64 + c] = run; run += v; }
    int tot = run;
    cellTot[l * 64 + c] = tot;
    int tiles = (tot + 63) >> 6;
    int x = tiles;
#pragma unroll
    for (int off = 1; off < 64; off <<= 1) { int y = __shfl_up(x, off, 64); if (c >= off) x += y; }
    int tileBase = x - tiles;
    csPad[l * 64 + c] = tileBase * 64;
    int* cot = cot_all + cTILEOFF[l];
    for (int i = 0; i < tiles; i++) cot[tileBase + i] = c;
    int nT = __shfl(x, 63, 64);
    int mt = cMT[l];
    for (int i = nT + c; i < mt; i += 64) cot[i] = -1;
}

// ---------------- node-degree scans ----------------
__global__ void k_nscan1(const int* __restrict__ dcnt, int* __restrict__ dbase, int* __restrict__ bsum) {
    int b = blockIdx.x;
    int l = lvl_n(b);
    int lb = b - cNBLKOFF[l];
    int n = cN[l];
    __shared__ int sh[256];
    int t = threadIdx.x;
    int i = lb * 256 + t;
    int v = (i < n) ? dcnt[cNOFF[l] + i] : 0;
    sh[t] = v;
    __syncthreads();
    for (int off = 1; off < 256; off <<= 1) {
        int y = (t >= off) ? sh[t - off] : 0;
        __syncthreads();
        sh[t] += y;
        __syncthreads();
    }
    if (i < n) dbase[cNOFF[l] + i] = sh[t] - v;
    if (t == 255) bsum[b] = sh[255];
}

__global__ void k_nscan2(const int* __restrict__ bsum, int* __restrict__ boff) {
    int l = blockIdx.x;
    int o = cNBLKOFF[l];
    int nb = cNBLKOFF[l + 1] - o;
    int t = threadIdx.x;
    int v = (t < nb) ? bsum[o + t] : 0;
    int s = v;
#pragma unroll
    for (int off = 1; off < 64; off <<= 1) { int y = __shfl_up(s, off, 64); if (t >= off) s += y; }
    int tot = __shfl(s, 63, 64);
    if (t < nb) boff[o + t] = s - v;
    int t2 = t + 64;
    int v2 = (t2 < nb) ? bsum[o + t2] : 0;
    int s2 = v2;
#pragma unroll
    for (int off = 1; off < 64; off <<= 1) { int y = __shfl_up(s2, off, 64); if (t >= off) s2 += y; }
    if (t2 < nb) boff[o + t2] = tot + s2 - v2;
}

// ---- merged scatter: one edge pass -> cbrec (cell order), darec (dst order), cpos ----
__global__ void k_scatter(P5f PS, P5i EI, const int* __restrict__ bb, const int* __restrict__ csPad,
                          const int* __restrict__ dbase, const int* __restrict__ boff,
                          int* __restrict__ rank,
                          int4* __restrict__ cbrec, int4* __restrict__ darec,
                          int* __restrict__ cpos) {
    int b = blockIdx.x;
    int l = lvl_e(b);
    int lb = b - cEBLKOFF[l];
    int E = cE[l];
    __shared__ int base[64];
    __shared__ int cnt[64];
    int t = threadIdx.x;
    if (t < 64) { base[t] = bb[(size_t)b * 64 + t] + csPad[l * 64 + t]; cnt[t] = 0; }
    __syncthreads();
    int e = lb * 256 + t;
    if (e >= E) return;
    const float* ps = PS.p[l];
    float v0 = ps[e * 3] * 4.f, v1 = ps[e * 3 + 1] * 4.f, v2 = ps[e * 3 + 2] * 4.f;
    float f0 = floorf(v0), f1v = floorf(v1), f2v = floorf(v2);
    int c = (int)f0 * 16 + (int)f1v * 4 + (int)f2v;
    int r = atomicAdd(&cnt[c], 1);
    int posc = base[c] + r;
    const int* ei = EI.p[l];
    int src = ei[e];
    int dst = ei[E + e];
    int posd = dbase[cNOFF[l] + dst] + boff[cNBLKOFF[l] + (dst >> 8)]
             + atomicAdd(&rank[cNOFF[l] + dst], 1);
    unsigned int fxfy = (unsigned int)__half_as_ushort(__float2half(v0 - f0))
                      | ((unsigned int)__half_as_ushort(__float2half(v1 - f1v)) << 16);
    unsigned int fzp  = (unsigned int)__half_as_ushort(__float2half(v2 - f2v));
    int4 rc;
    rc.x = src; rc.y = 0; rc.z = (int)fxfy; rc.w = (int)fzp;
    cbrec[cSEOFF[l] + posc] = rc;
    int4 rd;
    rd.x = src | (dst << 16); rd.y = c; rd.z = (int)fxfy; rd.w = (int)fzp;
    darec[cEOFF[l] + posd] = rd;
    cpos[cEOFF[l] + posd] = posc;
}

// -------- W + rootb swizzle (fused): fp32 -> MFMA B-frag bf16 ----------
__global__ void k_wswz(P5f WB, P5f RootB, uint4* __restrict__ hi4, uint4* __restrict__ rb) {
    int idx = blockIdx.x * 256 + threadIdx.x;
    if (idx >= 290304) return;
    if (idx < 288000) {
        int l = (idx >= 224000) ? 4 : (idx >= 160000) ? 3 : (idx >= 96000) ? 2 : (idx >= 32000) ? 1 : 0;
        int local = idx - cWOFF[l];
        int T = l ? 2 : 1, C = l ? 64 : 32;
        int lane = local & 63;
        int blk = (local >> 6) & 3;
        int rest = local >> 8;
        int st = rest % T, s = rest / T;
        int q = lane >> 4, n = blk * 16 + (lane & 15);
        const float* W = WB.p[l];
        union { ushortT u[8]; uint4 v; } ph;
#pragma unroll
        for (int j = 0; j < 8; j++) {
            int k = st * 32 + q * 8 + j;
            ph.u[j] = f2bf(W[((size_t)s * C + k) * 64 + n]);
        }
        hi4[idx] = ph.v;
    } else {
        int id2 = idx - 288000;
        int l = (id2 >= 1792) ? 4 : (id2 >= 1280) ? 3 : (id2 >= 768) ? 2 : (id2 >= 256) ? 1 : 0;
        int local = id2 - cRBOFF[l];
        int lane = local & 63;
        int w = (local >> 6) & 3;
        int st = local >> 8;
        int q = lane >> 4, n = w * 16 + (lane & 15);
        const float* R = RootB.p[l];
        union { ushortT u[8]; uint4 v; } ph;
#pragma unroll
        for (int j = 0; j < 8; j++) {
            int k = st * 32 + q * 8 + j;
            ph.u[j] = f2bf(R[k * 64 + n]);
        }
        rb[id2] = ph.v;
    }
}

// ---- Fused Conv A: LDS-staged edges, corner-parallel, ILP'd S@Wa tail ---------------
template<int C1>
__device__ __forceinline__ void conv_a_gemm(const float* __restrict__ S, const float* __restrict__ Wa,
                                            const float* __restrict__ x, const float* __restrict__ ra,
                                            const float* __restrict__ ba, const int* __restrict__ dcl,
                                            int node0, int nn, ushortT* __restrict__ f1bfl, int t) {
    int ch = t % C1;
    int npp = 256 / C1;
    float bias = ba[ch];
    float root = ra[ch];
    for (int node = t / C1; node < nn; node += npp) {
        const float* Sr = S + node * 126;
        float s0 = 0.f, s1 = 0.f, s2 = 0.f, s3 = 0.f;
#pragma unroll
        for (int k = 0; k < 124; k += 4) {
            s0 = fmaf(Sr[k],     Wa[k * C1 + ch],       s0);
            s1 = fmaf(Sr[k + 1], Wa[(k + 1) * C1 + ch], s1);
            s2 = fmaf(Sr[k + 2], Wa[(k + 2) * C1 + ch], s2);
            s3 = fmaf(Sr[k + 3], Wa[(k + 3) * C1 + ch], s3);
        }
        float s = ((s0 + s1) + (s2 + s3)) + Sr[124] * Wa[124 * C1 + ch];
        int gnode = node0 + node;
        int dv = dcl[gnode];
        float d = (float)(dv > 1 ? dv : 1);
        float o = s / d + x[gnode] * root + bias;
        f1bfl[(size_t)gnode * C1 + ch] = f2bf(fmaxf(o, 0.f));
    }
}

__launch_bounds__(256)
__global__ void conv_a_fused(P5f X, P5f WA, P5f RootA, P5f BiasA,
                             const int4* __restrict__ darec,
                             const int* __restrict__ dbase, const int* __restrict__ boff,
                             const int* __restrict__ dcnt, ushortT* __restrict__ f1bf) {
    __shared__ float S[16 * 126];
    __shared__ int infoS[256];
    __shared__ unsigned int fxyS[256];
    __shared__ unsigned int fzS[256];
    __shared__ float xsS[256];
    int b = blockIdx.x;
    int l = (b >= cABLK[4]) ? 4 : (b >= cABLK[3]) ? 3 : (b >= cABLK[2]) ? 2 : (b >= cABLK[1]) ? 1 : 0;
    int node0 = (b - cABLK[l]) * 16;
    int n = cN[l];
    int nn = n - node0; if (nn > 16) nn = 16;
    int t = threadIdx.x;
    for (int i = t; i < 16 * 126; i += 256) S[i] = 0.f;
    const int* db = dbase + cNOFF[l];
    const int* bo = boff + cNBLKOFF[l];
    int estart = db[node0] + bo[node0 >> 8];
    int vend = node0 + nn;
    int eend = (vend >= n) ? cE[l] : (db[vend] + bo[vend >> 8]);
    const float* x = X.p[l];
    const int4* dr = darec + cEOFF[l];
    const int bx = t & 1, by = (t >> 1) & 1, bz = (t >> 2) & 1;
    for (int cs = estart; cs < eend; cs += 256) {
        int p = cs + t;
        if (p < eend) {
            int4 r = dr[p];
            infoS[t] = ((((unsigned int)r.x) >> 16) - node0) * 64 + r.y;
            fxyS[t] = (unsigned int)r.z;
            fzS[t] = (unsigned int)r.w;
            xsS[t] = x[r.x & 0xFFFF];
        }
        __syncthreads();
        int ne = eend - cs; if (ne > 256) ne = 256;
        for (int j = (t >> 3); j < ne; j += 32) {
            int info = infoS[j];
            int nl = info >> 6, cell = info & 63;
            unsigned int uz = fxyS[j];
            float fx = h2f_lo(uz), fy = h2f_hi(uz), fz = h2f_lo(fzS[j]);
            float xs = xsS[j];
            int cx = cell >> 4, cy = (cell >> 2) & 3, cz = cell & 3;
            int slot = (cx + bx) * 25 + (cy + by) * 5 + (cz + bz);
            float wc = (bx ? fx : 1.f - fx) * (by ? fy : 1.f - fy) * (bz ? fz : 1.f - fz);
            atomicAdd(&S[nl * 126 + slot], wc * xs);
        }
        __syncthreads();
    }
    if (l == 0)
        conv_a_gemm<32>(S, WA.p[0], X.p[0], RootA.p[0], BiasA.p[0], dcnt + cNOFF[0],
                        node0, nn, f1bf + cF1OFF[0], t);
    else
        conv_a_gemm<64>(S, WA.p[l], X.p[l], RootA.p[l], BiasA.p[l], dcnt + cNOFF[l],
                        node0, nn, f1bf + cF1OFF[l], t);
}

// ---- R-gemm: f2 = f1bf @ rootb (bf16 MFMA), per-64-node tiles -----------------------
__launch_bounds__(256)
__global__ void k_rgemm(const ushortT* __restrict__ f1bf, const uint4* __restrict__ rb,
                        float* __restrict__ f2) {
    int b = blockIdx.x;
    int l = (b >= cRGB[4]) ? 4 : (b >= cRGB[3]) ? 3 : (b >= cRGB[2]) ? 2 : (b >= cRGB[1]) ? 1 : 0;
    int node0 = (b - cRGB[l]) * 64;
    int n = cN[l];
    int nn = n - node0; if (nn > 64) nn = 64;
    int t = threadIdx.x;
    int lane = t & 63, w = t >> 6;
    int q = lane >> 4, m = lane & 15;
    const int CIN = l ? 64 : 32;
    const int T = l ? 2 : 1;
    const ushortT* fl = f1bf + cF1OFF[l];
    const uint4* rbl = rb + cRBOFF[l];
    f32x4 C[4];
#pragma unroll
    for (int mt = 0; mt < 4; mt++) C[mt] = (f32x4){0.f, 0.f, 0.f, 0.f};
    for (int st = 0; st < T; st++) {
        bf16x8 bh = __builtin_bit_cast(bf16x8, rbl[(st * 4 + w) * 64 + lane]);
#pragma unroll
        for (int mt = 0; mt < 4; mt++) {
            int row = 16 * mt + m;
            int nr = node0 + row; if (nr > n - 1) nr = n - 1;
            bf16x8 a = *(const bf16x8*)&fl[(size_t)nr * CIN + st * 32 + q * 8];
            C[mt] = __builtin_amdgcn_mfma_f32_16x16x32_bf16(a, bh, C[mt], 0, 0, 0);
        }
    }
#pragma unroll
    for (int mt = 0; mt < 4; mt++)
#pragma unroll
        for (int rr = 0; rr < 4; rr++) {
            int row = 16 * mt + q * 4 + rr;
            if (row < nn)
                f2[(size_t)(cNOFF[l] + node0 + row) * 64 + 16 * w + m] = C[mt][rr];
        }
}

// ---- Conv B tile: LDS-resident row weights (low VGPR), z-paired epilogue ------------
template<int CIN>
__device__ __forceinline__ void conv_b_tile(
    const ushortT* __restrict__ f1bfl, const int4* __restrict__ cbrec_l,
    const uint4* __restrict__ whiL,
    int cell, int tb, int valid, __half* __restrict__ pout,
    float* wxyS /*4*64*/, float* fzS /*64*/, int* srcs) {
    const int T = CIN / 32;
    int t = threadIdx.x;
    if (t < 64) {
        bool v = t < valid;
        int4 r;
        if (v) r = cbrec_l[tb + t]; else { r.x = 0; r.y = 0; r.z = 0; r.w = 0; }
        srcs[t] = r.x;
        unsigned int uz = (unsigned int)r.z;
        float fx = h2f_lo(uz), fy = h2f_hi(uz);
        float gx = 1.f - fx, gy = 1.f - fy;
        wxyS[0 * 64 + t] = gx * gy;
        wxyS[1 * 64 + t] = fx * gy;
        wxyS[2 * 64 + t] = gx * fy;
        wxyS[3 * 64 + t] = fx * fy;
        fzS[t] = h2f_lo((unsigned int)r.w);
    }
    __syncthreads();

    int lane = t & 63, w = t >> 6;
    int q = lane >> 4, m = lane & 15;

    bf16x8 ahr[4][T];
#pragma unroll
    for (int mt = 0; mt < 4; mt++) {
        int src = srcs[16 * mt + m];
#pragma unroll
        for (int st = 0; st < T; st++)
            ahr[mt][st] = *(const bf16x8*)&f1bfl[(size_t)src * CIN + st * 32 + q * 8];
    }
    float fzr[16];
#pragma unroll
    for (int mt = 0; mt < 4; mt++)
#pragma unroll
        for (int rr = 0; rr < 4; rr++)
            fzr[mt * 4 + rr] = fzS[16 * mt + q * 4 + rr];

    int cx = cell >> 4, cy = (cell >> 2) & 3, cz = cell & 3;
    f32x4 acc[4];
#pragma unroll
    for (int mt = 0; mt < 4; mt++) acc[mt] = (f32x4){0.f, 0.f, 0.f, 0.f};

#pragma unroll
    for (int xy = 0; xy < 4; xy++) {
        const int bx = xy & 1, by = xy >> 1;
        int slot0 = (cx + bx) * 25 + (cy + by) * 5 + cz;  // bz=0; bz=1 is slot0+1
        f32x4 C0[4], C1[4];
#pragma unroll
        for (int mt = 0; mt < 4; mt++) {
            C0[mt] = (f32x4){0.f, 0.f, 0.f, 0.f};
            C1[mt] = (f32x4){0.f, 0.f, 0.f, 0.f};
        }
#pragma unroll
        for (int st = 0; st < T; st++) {
            bf16x8 b0 = __builtin_bit_cast(bf16x8, whiL[((size_t)(slot0 * T + st) * 4 + w) * 64 + lane]);
            bf16x8 b1 = __builtin_bit_cast(bf16x8, whiL[((size_t)((slot0 + 1) * T + st) * 4 + w) * 64 + lane]);
#pragma unroll
            for (int mt = 0; mt < 4; mt++) {
                C0[mt] = __builtin_amdgcn_mfma_f32_16x16x32_bf16(ahr[mt][st], b0, C0[mt], 0, 0, 0);
                C1[mt] = __builtin_amdgcn_mfma_f32_16x16x32_bf16(ahr[mt][st], b1, C1[mt], 0, 0, 0);
            }
        }
        const float* wrow = &wxyS[xy * 64];
#pragma unroll
        for (int mt = 0; mt < 4; mt++)
#pragma unroll
            for (int rr = 0; rr < 4; rr++) {
                int i16 = mt * 4 + rr;
                float wxy = wrow[16 * mt + q * 4 + rr];   // LDS broadcast (4 addrs/wave)
                float dlt = C1[mt][rr] - C0[mt][rr];
                float tt = fmaf(fzr[i16], dlt, C0[mt][rr]);
                acc[mt][rr] = fmaf(wxy, tt, acc[mt][rr]);
            }
    }
    // coalesced cell-order store
#pragma unroll
    for (int mt = 0; mt < 4; mt++)
#pragma unroll
        for (int rr = 0; rr < 4; rr++) {
            int row = 16 * mt + q * 4 + rr;
            pout[(size_t)(tb + row) * 64 + 16 * w + m] = __float2half(acc[mt][rr]);
        }
}

// ---- merged conv B: all 10008 tiles (l0 + l1-4), disjoint Ph regions ----------------
__launch_bounds__(256)
__global__ void conv_b_all(const ushortT* __restrict__ f1bf, const int4* __restrict__ cbrec,
                           const uint4* __restrict__ whi,
                           const int* __restrict__ cot, const int* __restrict__ csPad,
                           const int* __restrict__ cellTot, __half* __restrict__ Ph) {
    __shared__ float wxyS[4 * 64];
    __shared__ float fzS[64];
    __shared__ int srcs[64];
    int blk = blockIdx.x;
    if (blk < 5064) {
        int cell = cot[blk];
        if (cell < 0) return;
        int tb = blk * 64;
        int valid = csPad[cell] + cellTot[cell] - tb;
        if (valid > 64) valid = 64;
        conv_b_tile<32>(f1bf, cbrec, whi, cell, tb, valid, Ph, wxyS, fzS, srcs);
    } else {
        const int TB2[4] = {0, 2564, 3878, 4567};
        int b2 = blk - 5064;
        int li = (b2 >= 4567) ? 3 : (b2 >= 3878) ? 2 : (b2 >= 2564) ? 1 : 0;
        int l = li + 1;
        int tile = b2 - TB2[li];
        int cell = cot[cTILEOFF[l] + tile];
        if (cell < 0) return;
        int tb = tile * 64;
        int valid = csPad[l * 64 + cell] + cellTot[l * 64 + cell] - tb;
        if (valid > 64) valid = 64;
        conv_b_tile<64>(f1bf + cF1OFF[l], cbrec + cSEOFF[l], whi + cWOFF[l],
                        cell, tb, valid, Ph + (size_t)cSEOFF[l] * 64,
                        wxyS, fzS, srcs);
    }
}

// ---- merged node epilogue: one node per wave; gather Ph + R + bias + relu -> f2 -----
__launch_bounds__(256)
__global__ void node_b_all(const __half* __restrict__ Ph, const int* __restrict__ cpos,
                           const int* __restrict__ dbase, const int* __restrict__ boff,
                           const int* __restrict__ dcnt, P5f BiasB, float* __restrict__ f2) {
    int lane = threadIdx.x & 63;
    int blk = blockIdx.x;
    int l, node;
    if (blk < 5000) {
        l = 0;
        node = blk * 4 + (threadIdx.x >> 6);
        if (node >= 20000) return;
    } else {
        const int NB2[4] = {0, 2500, 3750, 4375};
        int b2 = blk - 5000;
        int li = (b2 >= 4375) ? 3 : (b2 >= 3750) ? 2 : (b2 >= 2500) ? 1 : 0;
        l = li + 1;
        node = (b2 - NB2[li]) * 4 + (threadIdx.x >> 6);
        if (node >= cN[l]) return;
    }
    int start = dbase[cNOFF[l] + node] + boff[cNBLKOFF[l] + (node >> 8)];
    int deg = dcnt[cNOFF[l] + node];
    const __half* PhL = Ph + (size_t)cSEOFF[l] * 64;
    const int* cposL = cpos + cEOFF[l];
    float* f2row = f2 + (size_t)(cNOFF[l] + node) * 64;
    float s0 = 0.f, s1 = 0.f;
    int k = 0;
    for (; k + 2 <= deg; k += 2) {
        int r0 = cposL[start + k];
        int r1 = cposL[start + k + 1];
        s0 += __half2float(PhL[(size_t)r0 * 64 + lane]);
        s1 += __half2float(PhL[(size_t)r1 * 64 + lane]);
    }
    if (k < deg) s0 += __half2float(PhL[(size_t)cposL[start + k] * 64 + lane]);
    float s = (s0 + s1) / (float)(deg > 1 ? deg : 1)
            + f2row[lane] + BiasB.p[l][lane];
    f2row[lane] = fmaxf(s, 0.f);
}

// ---------------- readout: run-accumulated graph mean sums ----------------
__launch_bounds__(256)
__global__ void k_read(const float* __restrict__ f2, P5i Batch,
                       float* __restrict__ hsum, float* __restrict__ gcnt) {
    const int RC[5] = {0, 1250, 1875, 2188, 2345};
    int t = threadIdx.x;
    int lane = t & 63;
    int w = blockIdx.x * 4 + (t >> 6);
    if (w >= 2424) return;
    int l = (w >= 2345) ? 4 : (w >= 2188) ? 3 : (w >= 1875) ? 2 : (w >= 1250) ? 1 : 0;
    int base = (w - RC[l]) * 16;
    int Nl = cN[l];
    int nn = Nl - base; if (nn > 16) nn = 16;
    const int* batch = Batch.p[l];
    const float* fb = f2 + (size_t)(cNOFF[l] + base) * 64;
    int curg = -1; float hacc = 0.f; int crun = 0;
    for (int j = 0; j < nn; j++) {
        int g = batch[base + j];
        if (g != curg) {
            if (curg >= 0) {
                atomicAdd(&hsum[curg * 320 + l * 64 + lane], hacc);
                if (lane == 0) atomicAdd(&gcnt[l * 64 + curg], (float)crun);
            }
            curg = g; hacc = 0.f; crun = 0;
        }
        hacc += fb[(size_t)j * 64 + lane];
        crun++;
    }
    if (curg >= 0) {
        atomicAdd(&hsum[curg * 320 + l * 64 + lane], hacc);
        if (lane == 0) atomicAdd(&gcnt[l * 64 + curg], (float)crun);
    }
}

// ---------------- FC + log_softmax: one block per graph ----------------
__global__ void fc_kernel(const float* __restrict__ hsum, const float* __restrict__ gcnt,
                          const float* __restrict__ fcw, const float* __restrict__ fcb,
                          float* __restrict__ out) {
    int g = blockIdx.x;
    int lane = threadIdx.x;  // 64
    float partial[10];
#pragma unroll
    for (int t = 0; t < 10; t++) partial[t] = 0.f;
#pragma unroll
    for (int k = 0; k < 5; k++) {
        int j = k * 64 + lane;
        float c = fmaxf(gcnt[k * 64 + g], 1.f);
        float h = hsum[g * 320 + j] / c;
        const float* fw = fcw + j * 10;
#pragma unroll
        for (int t = 0; t < 10; t++) partial[t] = fmaf(h, fw[t], partial[t]);
    }
#pragma unroll
    for (int off = 32; off >= 1; off >>= 1)
#pragma unroll
        for (int t = 0; t < 10; t++) partial[t] += __shfl_xor(partial[t], off, 64);
    if (lane == 0) {
        float logit[10];
#pragma unroll
        for (int t = 0; t < 10; t++) logit[t] = partial[t] + fcb[t];
        float m = logit[0];
#pragma unroll
        for (int t = 1; t < 10; t++) m = fmaxf(m, logit[t]);
        float sum = 0.f;
#pragma unroll
        for (int t = 0; t < 10; t++) sum += expf(logit[t] - m);
        float lse = m + logf(sum);
#pragma unroll
        for (int t = 0; t < 10; t++) out[g * 10 + t] = logit[t] - lse;
    }
}

extern "C" void kernel_launch(void* const* d_in, const int* in_sizes, int n_in,
                              void* d_out, int out_size, void* d_ws, size_t ws_size,
                              hipStream_t stream) {
    int* wsI = (int*)d_ws;
    int*   dcnt  = wsI;                          // 38750
    int*   rank  = dcnt + 38750;                 // 38750
    float* hsum  = (float*)(rank + 38750);       // 20480  (hsum[g*320 + l*64 + lane])
    float* gcnt  = hsum + 20480;                 // 320
    float* f2    = gcnt + 320;                   // 2,480,000 (R from rgemm)
    int*   dbase = (int*)(f2 + 2480000);         // 38750
    int*   bsum  = dbase + 38750;                // 160
    int*   boff  = bsum + 160;                   // 160
    int*   cpos  = boff + 160;                   // 620000
    int*   bb    = cpos + 620000;                // 155136
    int*   csPad = bb + 155136;                  // 320
    int*   cellTot = csPad + 320;                // 320
    int*   cot   = cellTot + 320;                // 10008
    int4*  cbrec = (int4*)(((size_t)(cot + 10008) + 15) & ~(size_t)15);   // 640512 recs
    int4*  darec = cbrec + 640512;               // 620000 recs
    ushortT* f1bf = (ushortT*)(darec + 620000);  // 1,840,000 ushorts
    uint4* whi   = (uint4*)(((size_t)(f1bf + 1840000) + 15) & ~(size_t)15);  // 288000
    uint4* rbsw  = whi + 288000;                 // 2304
    __half* Ph   = (__half*)(rbsw + 2304);       // 640512 rows of 64 (~82MB, DISJOINT per level)

    hipMemsetAsync(dcnt, 0, (size_t)(38750 * 2 + 20480 + 320) * sizeof(int), stream);

    P5f PS, X, WA, RootA, BiasA, WB, RootB, BiasB;
    P5i EI, Batch;
    for (int l = 0; l < 5; l++) {
        const int b = l * 10;
        X.p[l]     = (const float*)d_in[b + 0];
        PS.p[l]    = (const float*)d_in[b + 1];
        EI.p[l]    = (const int*)d_in[b + 2];
        Batch.p[l] = (const int*)d_in[b + 3];
        WA.p[l]    = (const float*)d_in[b + 4];
        RootA.p[l] = (const float*)d_in[b + 5];
        BiasA.p[l] = (const float*)d_in[b + 6];
        WB.p[l]    = (const float*)d_in[b + 7];
        RootB.p[l] = (const float*)d_in[b + 8];
        BiasB.p[l] = (const float*)d_in[b + 9];
    }

    // prep
    k_hist<<<2424, 256, 0, stream>>>(PS, EI, dcnt, bb);
    k_cellscan<<<5, 64, 0, stream>>>(bb, csPad, cellTot, cot);
    k_nscan1<<<154, 256, 0, stream>>>(dcnt, dbase, bsum);
    k_nscan2<<<5, 64, 0, stream>>>(bsum, boff);
    k_scatter<<<2424, 256, 0, stream>>>(PS, EI, bb, csPad, dbase, boff, rank,
                                        cbrec, darec, cpos);
    k_wswz<<<1134, 256, 0, stream>>>(WB, RootB, whi, rbsw);

    // conv A (all levels) -> f1bf
    conv_a_fused<<<2424, 256, 0, stream>>>(X, WA, RootA, BiasA, darec,
                                           dbase, boff, dcnt, f1bf);

    // R = f1 @ rootb into f2 (MFMA)
    k_rgemm<<<609, 256, 0, stream>>>(f1bf, rbsw, f2);

    // conv B (ALL levels, one dispatch) -> Ph; node epilogue (ALL levels) -> f2
    conv_b_all<<<10008, 256, 0, stream>>>(f1bf, cbrec, whi, cot, csPad, cellTot, Ph);
    node_b_all<<<9688, 256, 0, stream>>>(Ph, cpos, dbase, boff, dcnt, BiasB, f2);

    // readout + FC
    k_read<<<606, 256, 0, stream>>>(f2, Batch, hsum, gcnt);
    fc_kernel<<<64, 64, 0, stream>>>(hsum, gcnt, (const float*)d_in[50], (const float*)d_in[51],
                                     (float*)d_out);
}

// Round 15
// 456.802 us; speedup vs baseline: 1.2259x; 1.0360x over previous
//
#include <hip/hip_runtime.h>
#include <hip/hip_fp16.h>
#include <math.h>

#define NUM_GRAPHS 64

typedef unsigned short ushortT;
typedef __attribute__((ext_vector_type(8))) short bf16x8;
typedef __attribute__((ext_vector_type(4))) float f32x4;

// ---- static level tables ----
constexpr int cN[5]       = {20000, 10000, 5000, 2500, 1250};
constexpr int cE[5]       = {320000, 160000, 80000, 40000, 20000};
constexpr int cNOFF[6]    = {0, 20000, 30000, 35000, 37500, 38750};
constexpr int cEOFF[6]    = {0, 320000, 480000, 560000, 600000, 620000};
constexpr int cEBLKOFF[6] = {0, 1250, 1875, 2188, 2345, 2424};
constexpr int cNBLKOFF[6] = {0, 79, 119, 139, 149, 154};
constexpr int cMT[5]      = {5064, 2564, 1314, 689, 377};
constexpr int cTILEOFF[6] = {0, 5064, 7628, 8942, 9631, 10008};
constexpr int cSEOFF[6]   = {0, 324096, 488192, 572288, 616384, 640512};
constexpr int cF1OFF[6]   = {0, 640000, 1280000, 1600000, 1760000, 1840000};
constexpr int cWOFF[6]    = {0, 32000, 96000, 160000, 224000, 288000};
constexpr int cABLK[6]    = {0, 1250, 1875, 2188, 2345, 2424};   // ceil(N/16) prefix
constexpr int cRBOFF[5]   = {0, 256, 768, 1280, 1792};           // rootb swizzle uint4 offsets
constexpr int cWAOFF[6]   = {0, 512, 1536, 2560, 3584, 4608};    // Wa swizzle uint4 offsets
constexpr int cRGB[6]     = {0, 313, 470, 549, 589, 609};        // ceil(N/64) prefix

struct P5f { const float* p[5]; };
struct P5i { const int* p[5]; };

__device__ __forceinline__ int lvl_e(int b) {
    return (b >= cEBLKOFF[4]) ? 4 : (b >= cEBLKOFF[3]) ? 3 : (b >= cEBLKOFF[2]) ? 2 : (b >= cEBLKOFF[1]) ? 1 : 0;
}
__device__ __forceinline__ int lvl_n(int b) {
    return (b >= cNBLKOFF[4]) ? 4 : (b >= cNBLKOFF[3]) ? 3 : (b >= cNBLKOFF[2]) ? 2 : (b >= cNBLKOFF[1]) ? 1 : 0;
}

__device__ __forceinline__ ushortT f2bf(float f) {
    union { float f; unsigned int u; } v; v.f = f;
    unsigned int r = (v.u + 0x7FFFu + ((v.u >> 16) & 1u)) >> 16;
    return (ushortT)r;
}
__device__ __forceinline__ float h2f_lo(unsigned int u) {
    return __half2float(__ushort_as_half((ushortT)(u & 0xFFFFu)));
}
__device__ __forceinline__ float h2f_hi(unsigned int u) {
    return __half2float(__ushort_as_half((ushortT)(u >> 16)));
}

// ---------------- prep: per-block cell histogram + dst degree count ----------------
__global__ void k_hist(P5f PS, P5i EI, int* __restrict__ dcnt, int* __restrict__ bb) {
    int b = blockIdx.x;
    int l = lvl_e(b);
    int lb = b - cEBLKOFF[l];
    int E = cE[l];
    __shared__ int h[64];
    int t = threadIdx.x;
    if (t < 64) h[t] = 0;
    __syncthreads();
    int e = lb * 256 + t;
    if (e < E) {
        atomicAdd(&dcnt[cNOFF[l] + EI.p[l][E + e]], 1);
        const float* ps = PS.p[l];
        int c = (int)floorf(ps[e * 3] * 4.f) * 16 + (int)floorf(ps[e * 3 + 1] * 4.f) * 4
              + (int)floorf(ps[e * 3 + 2] * 4.f);
        atomicAdd(&h[c], 1);
    }
    __syncthreads();
    if (t < 64) bb[(size_t)b * 64 + t] = h[t];
}

// ---------------- cell scan ----------------
__global__ void k_cellscan(int* __restrict__ bb_all, int* __restrict__ csPad,
                           int* __restrict__ cellTot, int* __restrict__ cot_all) {
    int l = blockIdx.x;
    int c = threadIdx.x;
    int* bb = bb_all + (size_t)cEBLKOFF[l] * 64;
    int nblk = cEBLKOFF[l + 1] - cEBLKOFF[l];
    int run = 0;
    int b = 0;
    for (; b + 16 <= nblk; b += 16) {
        int v[16];
#pragma unroll
        for (int u = 0; u < 16; u++) v[u] = bb[(b + u) * 64 + c];
#pragma unroll
        for (int u = 0; u < 16; u++) { bb[(b + u) * 64 + c] = run; run += v[u]; }
    }
    for (; b < nblk; b++) { int v = bb[b * 64 + c]; bb[b * 64 + c] = run; run += v; }
    int tot = run;
    cellTot[l * 64 + c] = tot;
    int tiles = (tot + 63) >> 6;
    int x = tiles;
#pragma unroll
    for (int off = 1; off < 64; off <<= 1) { int y = __shfl_up(x, off, 64); if (c >= off) x += y; }
    int tileBase = x - tiles;
    csPad[l * 64 + c] = tileBase * 64;
    int* cot = cot_all + cTILEOFF[l];
    for (int i = 0; i < tiles; i++) cot[tileBase + i] = c;
    int nT = __shfl(x, 63, 64);
    int mt = cMT[l];
    for (int i = nT + c; i < mt; i += 64) cot[i] = -1;
}

// ---------------- node-degree scans ----------------
__global__ void k_nscan1(const int* __restrict__ dcnt, int* __restrict__ dbase, int* __restrict__ bsum) {
    int b = blockIdx.x;
    int l = lvl_n(b);
    int lb = b - cNBLKOFF[l];
    int n = cN[l];
    __shared__ int sh[256];
    int t = threadIdx.x;
    int i = lb * 256 + t;
    int v = (i < n) ? dcnt[cNOFF[l] + i] : 0;
    sh[t] = v;
    __syncthreads();
    for (int off = 1; off < 256; off <<= 1) {
        int y = (t >= off) ? sh[t - off] : 0;
        __syncthreads();
        sh[t] += y;
        __syncthreads();
    }
    if (i < n) dbase[cNOFF[l] + i] = sh[t] - v;
    if (t == 255) bsum[b] = sh[255];
}

__global__ void k_nscan2(const int* __restrict__ bsum, int* __restrict__ boff) {
    int l = blockIdx.x;
    int o = cNBLKOFF[l];
    int nb = cNBLKOFF[l + 1] - o;
    int t = threadIdx.x;
    int v = (t < nb) ? bsum[o + t] : 0;
    int s = v;
#pragma unroll
    for (int off = 1; off < 64; off <<= 1) { int y = __shfl_up(s, off, 64); if (t >= off) s += y; }
    int tot = __shfl(s, 63, 64);
    if (t < nb) boff[o + t] = s - v;
    int t2 = t + 64;
    int v2 = (t2 < nb) ? bsum[o + t2] : 0;
    int s2 = v2;
#pragma unroll
    for (int off = 1; off < 64; off <<= 1) { int y = __shfl_up(s2, off, 64); if (t >= off) s2 += y; }
    if (t2 < nb) boff[o + t2] = tot + s2 - v2;
}

// ---- merged scatter: one edge pass -> cbrec (cell order), darec (dst order), cpos ----
__global__ void k_scatter(P5f PS, P5i EI, const int* __restrict__ bb, const int* __restrict__ csPad,
                          const int* __restrict__ dbase, const int* __restrict__ boff,
                          int* __restrict__ rank,
                          int4* __restrict__ cbrec, int4* __restrict__ darec,
                          int* __restrict__ cpos) {
    int b = blockIdx.x;
    int l = lvl_e(b);
    int lb = b - cEBLKOFF[l];
    int E = cE[l];
    __shared__ int base[64];
    __shared__ int cnt[64];
    int t = threadIdx.x;
    if (t < 64) { base[t] = bb[(size_t)b * 64 + t] + csPad[l * 64 + t]; cnt[t] = 0; }
    __syncthreads();
    int e = lb * 256 + t;
    if (e >= E) return;
    const float* ps = PS.p[l];
    float v0 = ps[e * 3] * 4.f, v1 = ps[e * 3 + 1] * 4.f, v2 = ps[e * 3 + 2] * 4.f;
    float f0 = floorf(v0), f1v = floorf(v1), f2v = floorf(v2);
    int c = (int)f0 * 16 + (int)f1v * 4 + (int)f2v;
    int r = atomicAdd(&cnt[c], 1);
    int posc = base[c] + r;
    const int* ei = EI.p[l];
    int src = ei[e];
    int dst = ei[E + e];
    int posd = dbase[cNOFF[l] + dst] + boff[cNBLKOFF[l] + (dst >> 8)]
             + atomicAdd(&rank[cNOFF[l] + dst], 1);
    unsigned int fxfy = (unsigned int)__half_as_ushort(__float2half(v0 - f0))
                      | ((unsigned int)__half_as_ushort(__float2half(v1 - f1v)) << 16);
    unsigned int fzp  = (unsigned int)__half_as_ushort(__float2half(v2 - f2v));
    int4 rc;
    rc.x = src; rc.y = 0; rc.z = (int)fxfy; rc.w = (int)fzp;
    cbrec[cSEOFF[l] + posc] = rc;
    int4 rd;
    rd.x = src | (dst << 16); rd.y = c; rd.z = (int)fxfy; rd.w = (int)fzp;
    darec[cEOFF[l] + posd] = rd;
    cpos[cEOFF[l] + posd] = posc;
}

// -------- W + rootb + Wa swizzle (fused): fp32 -> MFMA B-frag bf16 ----------
__global__ void k_wswz(P5f WB, P5f RootB, P5f WA,
                       uint4* __restrict__ hi4, uint4* __restrict__ rb, uint4* __restrict__ wa) {
    int idx = blockIdx.x * 256 + threadIdx.x;
    if (idx >= 294912) return;
    if (idx < 288000) {
        int l = (idx >= 224000) ? 4 : (idx >= 160000) ? 3 : (idx >= 96000) ? 2 : (idx >= 32000) ? 1 : 0;
        int local = idx - cWOFF[l];
        int T = l ? 2 : 1, C = l ? 64 : 32;
        int lane = local & 63;
        int blk = (local >> 6) & 3;
        int rest = local >> 8;
        int st = rest % T, s = rest / T;
        int q = lane >> 4, n = blk * 16 + (lane & 15);
        const float* W = WB.p[l];
        union { ushortT u[8]; uint4 v; } ph;
#pragma unroll
        for (int j = 0; j < 8; j++) {
            int k = st * 32 + q * 8 + j;
            ph.u[j] = f2bf(W[((size_t)s * C + k) * 64 + n]);
        }
        hi4[idx] = ph.v;
    } else if (idx < 290304) {
        int id2 = idx - 288000;
        int l = (id2 >= 1792) ? 4 : (id2 >= 1280) ? 3 : (id2 >= 768) ? 2 : (id2 >= 256) ? 1 : 0;
        int local = id2 - cRBOFF[l];
        int lane = local & 63;
        int w = (local >> 6) & 3;
        int st = local >> 8;
        int q = lane >> 4, n = w * 16 + (lane & 15);
        const float* R = RootB.p[l];
        union { ushortT u[8]; uint4 v; } ph;
#pragma unroll
        for (int j = 0; j < 8; j++) {
            int k = st * 32 + q * 8 + j;
            ph.u[j] = f2bf(R[k * 64 + n]);
        }
        rb[id2] = ph.v;
    } else {
        int id3 = idx - 290304;
        int l = (id3 >= cWAOFF[4]) ? 4 : (id3 >= cWAOFF[3]) ? 3 : (id3 >= cWAOFF[2]) ? 2 : (id3 >= cWAOFF[1]) ? 1 : 0;
        int local = id3 - cWAOFF[l];
        int C1 = l ? 64 : 32;
        int numN = C1 / 16;
        int lane = local & 63;
        int rest = local >> 6;       // st*numN + nb
        int nb = rest % numN, st = rest / numN;
        int q = lane >> 4, n = nb * 16 + (lane & 15);
        const float* Wsrc = WA.p[l];
        union { ushortT u[8]; uint4 v; } ph;
#pragma unroll
        for (int j = 0; j < 8; j++) {
            int k = st * 32 + q * 8 + j;
            ph.u[j] = (k < 125) ? f2bf(Wsrc[k * C1 + n]) : (ushortT)0;
        }
        wa[id3] = ph.v;
    }
}

// ---- Fused Conv A: LDS-staged edges, corner-parallel scatter, MFMA S@Wa tail --------
__launch_bounds__(256)
__global__ void conv_a_fused(P5f X, P5f RootA, P5f BiasA,
                             const int4* __restrict__ darec, const uint4* __restrict__ wasw,
                             const int* __restrict__ dbase, const int* __restrict__ boff,
                             const int* __restrict__ dcnt, ushortT* __restrict__ f1bf) {
    __shared__ float S[16 * 126];
    __shared__ ushortT Sbf[16 * 136];
    __shared__ int infoS[256];
    __shared__ unsigned int fxyS[256];
    __shared__ unsigned int fzS[256];
    __shared__ float xsS[256];
    int b = blockIdx.x;
    int l = (b >= cABLK[4]) ? 4 : (b >= cABLK[3]) ? 3 : (b >= cABLK[2]) ? 2 : (b >= cABLK[1]) ? 1 : 0;
    int node0 = (b - cABLK[l]) * 16;
    int n = cN[l];
    int nn = n - node0; if (nn > 16) nn = 16;
    int t = threadIdx.x;
    for (int i = t; i < 16 * 126; i += 256) S[i] = 0.f;
    const int* db = dbase + cNOFF[l];
    const int* bo = boff + cNBLKOFF[l];
    int estart = db[node0] + bo[node0 >> 8];
    int vend = node0 + nn;
    int eend = (vend >= n) ? cE[l] : (db[vend] + bo[vend >> 8]);
    const float* x = X.p[l];
    const int4* dr = darec + cEOFF[l];
    const int bx = t & 1, by = (t >> 1) & 1, bz = (t >> 2) & 1;
    for (int cs = estart; cs < eend; cs += 256) {
        int p = cs + t;
        if (p < eend) {
            int4 r = dr[p];
            infoS[t] = ((((unsigned int)r.x) >> 16) - node0) * 64 + r.y;
            fxyS[t] = (unsigned int)r.z;
            fzS[t] = (unsigned int)r.w;
            xsS[t] = x[r.x & 0xFFFF];
        }
        __syncthreads();
        int ne = eend - cs; if (ne > 256) ne = 256;
        for (int j = (t >> 3); j < ne; j += 32) {
            int info = infoS[j];
            int nl = info >> 6, cell = info & 63;
            unsigned int uz = fxyS[j];
            float fx = h2f_lo(uz), fy = h2f_hi(uz), fz = h2f_lo(fzS[j]);
            float xs = xsS[j];
            int cx = cell >> 4, cy = (cell >> 2) & 3, cz = cell & 3;
            int slot = (cx + bx) * 25 + (cy + by) * 5 + (cz + bz);
            float wc = (bx ? fx : 1.f - fx) * (by ? fy : 1.f - fy) * (bz ? fz : 1.f - fz);
            atomicAdd(&S[nl * 126 + slot], wc * xs);
        }
        __syncthreads();
    }
    // convert S -> bf16 LDS tile (padded stride 136)
    for (int i = t; i < 16 * 128; i += 256) {
        int node = i >> 7, k = i & 127;
        float v = (k < 126) ? S[node * 126 + k] : 0.f;
        Sbf[node * 136 + k] = f2bf(v);
    }
    __syncthreads();
    // GEMM: wave w computes cols [16w, 16w+16)
    int lane = t & 63, w = t >> 6;
    int C1 = l ? 64 : 32;
    int numN = C1 >> 4;
    if (w < numN) {
        int q = lane >> 4, m = lane & 15;
        const uint4* wl = wasw + cWAOFF[l];
        f32x4 acc = (f32x4){0.f, 0.f, 0.f, 0.f};
#pragma unroll
        for (int st = 0; st < 4; st++) {
            bf16x8 a = *(const bf16x8*)&Sbf[m * 136 + st * 32 + q * 8];
            bf16x8 bw = __builtin_bit_cast(bf16x8, wl[(st * numN + w) * 64 + lane]);
            acc = __builtin_amdgcn_mfma_f32_16x16x32_bf16(a, bw, acc, 0, 0, 0);
        }
        int ch = w * 16 + m;
        float rv = RootA.p[l][ch], bv = BiasA.p[l][ch];
        const int* dcl = dcnt + cNOFF[l];
        ushortT* f1bfl = f1bf + cF1OFF[l];
#pragma unroll
        for (int rr = 0; rr < 4; rr++) {
            int row = q * 4 + rr;
            if (row < nn) {
                int gnode = node0 + row;
                int dv = dcl[gnode];
                float d = (float)(dv > 1 ? dv : 1);
                float o = acc[rr] / d + x[gnode] * rv + bv;
                f1bfl[(size_t)gnode * C1 + ch] = f2bf(fmaxf(o, 0.f));
            }
        }
    }
}

// ---- R-gemm: f2 = f1bf @ rootb (bf16 MFMA), per-64-node tiles -----------------------
__launch_bounds__(256)
__global__ void k_rgemm(const ushortT* __restrict__ f1bf, const uint4* __restrict__ rb,
                        float* __restrict__ f2) {
    int b = blockIdx.x;
    int l = (b >= cRGB[4]) ? 4 : (b >= cRGB[3]) ? 3 : (b >= cRGB[2]) ? 2 : (b >= cRGB[1]) ? 1 : 0;
    int node0 = (b - cRGB[l]) * 64;
    int n = cN[l];
    int nn = n - node0; if (nn > 64) nn = 64;
    int t = threadIdx.x;
    int lane = t & 63, w = t >> 6;
    int q = lane >> 4, m = lane & 15;
    const int CIN = l ? 64 : 32;
    const int T = l ? 2 : 1;
    const ushortT* fl = f1bf + cF1OFF[l];
    const uint4* rbl = rb + cRBOFF[l];
    f32x4 C[4];
#pragma unroll
    for (int mt = 0; mt < 4; mt++) C[mt] = (f32x4){0.f, 0.f, 0.f, 0.f};
    for (int st = 0; st < T; st++) {
        bf16x8 bh = __builtin_bit_cast(bf16x8, rbl[(st * 4 + w) * 64 + lane]);
#pragma unroll
        for (int mt = 0; mt < 4; mt++) {
            int row = 16 * mt + m;
            int nr = node0 + row; if (nr > n - 1) nr = n - 1;
            bf16x8 a = *(const bf16x8*)&fl[(size_t)nr * CIN + st * 32 + q * 8];
            C[mt] = __builtin_amdgcn_mfma_f32_16x16x32_bf16(a, bh, C[mt], 0, 0, 0);
        }
    }
#pragma unroll
    for (int mt = 0; mt < 4; mt++)
#pragma unroll
        for (int rr = 0; rr < 4; rr++) {
            int row = 16 * mt + q * 4 + rr;
            if (row < nn)
                f2[(size_t)(cNOFF[l] + node0 + row) * 64 + 16 * w + m] = C[mt][rr];
        }
}

// ---- Conv B tile: LDS-resident row weights (low VGPR), z-paired epilogue ------------
template<int CIN>
__device__ __forceinline__ void conv_b_tile(
    const ushortT* __restrict__ f1bfl, const int4* __restrict__ cbrec_l,
    const uint4* __restrict__ whiL,
    int cell, int tb, int valid, __half* __restrict__ pout,
    float* wxyS /*4*64*/, float* fzS /*64*/, int* srcs) {
    const int T = CIN / 32;
    int t = threadIdx.x;
    if (t < 64) {
        bool v = t < valid;
        int4 r;
        if (v) r = cbrec_l[tb + t]; else { r.x = 0; r.y = 0; r.z = 0; r.w = 0; }
        srcs[t] = r.x;
        unsigned int uz = (unsigned int)r.z;
        float fx = h2f_lo(uz), fy = h2f_hi(uz);
        float gx = 1.f - fx, gy = 1.f - fy;
        wxyS[0 * 64 + t] = gx * gy;
        wxyS[1 * 64 + t] = fx * gy;
        wxyS[2 * 64 + t] = gx * fy;
        wxyS[3 * 64 + t] = fx * fy;
        fzS[t] = h2f_lo((unsigned int)r.w);
    }
    __syncthreads();

    int lane = t & 63, w = t >> 6;
    int q = lane >> 4, m = lane & 15;

    bf16x8 ahr[4][T];
#pragma unroll
    for (int mt = 0; mt < 4; mt++) {
        int src = srcs[16 * mt + m];
#pragma unroll
        for (int st = 0; st < T; st++)
            ahr[mt][st] = *(const bf16x8*)&f1bfl[(size_t)src * CIN + st * 32 + q * 8];
    }
    float fzr[16];
#pragma unroll
    for (int mt = 0; mt < 4; mt++)
#pragma unroll
        for (int rr = 0; rr < 4; rr++)
            fzr[mt * 4 + rr] = fzS[16 * mt + q * 4 + rr];

    int cx = cell >> 4, cy = (cell >> 2) & 3, cz = cell & 3;
    f32x4 acc[4];
#pragma unroll
    for (int mt = 0; mt < 4; mt++) acc[mt] = (f32x4){0.f, 0.f, 0.f, 0.f};

#pragma unroll
    for (int xy = 0; xy < 4; xy++) {
        const int bx = xy & 1, by = xy >> 1;
        int slot0 = (cx + bx) * 25 + (cy + by) * 5 + cz;  // bz=0; bz=1 is slot0+1
        f32x4 C0[4], C1[4];
#pragma unroll
        for (int mt = 0; mt < 4; mt++) {
            C0[mt] = (f32x4){0.f, 0.f, 0.f, 0.f};
            C1[mt] = (f32x4){0.f, 0.f, 0.f, 0.f};
        }
#pragma unroll
        for (int st = 0; st < T; st++) {
            bf16x8 b0 = __builtin_bit_cast(bf16x8, whiL[((size_t)(slot0 * T + st) * 4 + w) * 64 + lane]);
            bf16x8 b1 = __builtin_bit_cast(bf16x8, whiL[((size_t)((slot0 + 1) * T + st) * 4 + w) * 64 + lane]);
#pragma unroll
            for (int mt = 0; mt < 4; mt++) {
                C0[mt] = __builtin_amdgcn_mfma_f32_16x16x32_bf16(ahr[mt][st], b0, C0[mt], 0, 0, 0);
                C1[mt] = __builtin_amdgcn_mfma_f32_16x16x32_bf16(ahr[mt][st], b1, C1[mt], 0, 0, 0);
            }
        }
        const float* wrow = &wxyS[xy * 64];
#pragma unroll
        for (int mt = 0; mt < 4; mt++)
#pragma unroll
            for (int rr = 0; rr < 4; rr++) {
                int i16 = mt * 4 + rr;
                float wxy = wrow[16 * mt + q * 4 + rr];   // LDS broadcast (4 addrs/wave)
                float dlt = C1[mt][rr] - C0[mt][rr];
                float tt = fmaf(fzr[i16], dlt, C0[mt][rr]);
                acc[mt][rr] = fmaf(wxy, tt, acc[mt][rr]);
            }
    }
    // coalesced cell-order store
#pragma unroll
    for (int mt = 0; mt < 4; mt++)
#pragma unroll
        for (int rr = 0; rr < 4; rr++) {
            int row = 16 * mt + q * 4 + rr;
            pout[(size_t)(tb + row) * 64 + 16 * w + m] = __float2half(acc[mt][rr]);
        }
}

// ---- merged conv B: all 10008 tiles (l0 + l1-4), disjoint Ph regions ----------------
__launch_bounds__(256)
__global__ void conv_b_all(const ushortT* __restrict__ f1bf, const int4* __restrict__ cbrec,
                           const uint4* __restrict__ whi,
                           const int* __restrict__ cot, const int* __restrict__ csPad,
                           const int* __restrict__ cellTot, __half* __restrict__ Ph) {
    __shared__ float wxyS[4 * 64];
    __shared__ float fzS[64];
    __shared__ int srcs[64];
    int blk = blockIdx.x;
    if (blk < 5064) {
        int cell = cot[blk];
        if (cell < 0) return;
        int tb = blk * 64;
        int valid = csPad[cell] + cellTot[cell] - tb;
        if (valid > 64) valid = 64;
        conv_b_tile<32>(f1bf, cbrec, whi, cell, tb, valid, Ph, wxyS, fzS, srcs);
    } else {
        const int TB2[4] = {0, 2564, 3878, 4567};
        int b2 = blk - 5064;
        int li = (b2 >= 4567) ? 3 : (b2 >= 3878) ? 2 : (b2 >= 2564) ? 1 : 0;
        int l = li + 1;
        int tile = b2 - TB2[li];
        int cell = cot[cTILEOFF[l] + tile];
        if (cell < 0) return;
        int tb = tile * 64;
        int valid = csPad[l * 64 + cell] + cellTot[l * 64 + cell] - tb;
        if (valid > 64) valid = 64;
        conv_b_tile<64>(f1bf + cF1OFF[l], cbrec + cSEOFF[l], whi + cWOFF[l],
                        cell, tb, valid, Ph + (size_t)cSEOFF[l] * 64,
                        wxyS, fzS, srcs);
    }
}

// ---- merged node epilogue: one node per wave; gather Ph + R + bias + relu -> f2 -----
__launch_bounds__(256)
__global__ void node_b_all(const __half* __restrict__ Ph, const int* __restrict__ cpos,
                           const int* __restrict__ dbase, const int* __restrict__ boff,
                           const int* __restrict__ dcnt, P5f BiasB, float* __restrict__ f2) {
    int lane = threadIdx.x & 63;
    int blk = blockIdx.x;
    int l, node;
    if (blk < 5000) {
        l = 0;
        node = blk * 4 + (threadIdx.x >> 6);
        if (node >= 20000) return;
    } else {
        const int NB2[4] = {0, 2500, 3750, 4375};
        int b2 = blk - 5000;
        int li = (b2 >= 4375) ? 3 : (b2 >= 3750) ? 2 : (b2 >= 2500) ? 1 : 0;
        l = li + 1;
        node = (b2 - NB2[li]) * 4 + (threadIdx.x >> 6);
        if (node >= cN[l]) return;
    }
    int start = dbase[cNOFF[l] + node] + boff[cNBLKOFF[l] + (node >> 8)];
    int deg = dcnt[cNOFF[l] + node];
    const __half* PhL = Ph + (size_t)cSEOFF[l] * 64;
    const int* cposL = cpos + cEOFF[l];
    float* f2row = f2 + (size_t)(cNOFF[l] + node) * 64;
    float s0 = 0.f, s1 = 0.f, s2 = 0.f, s3 = 0.f;
    int k = 0;
    for (; k + 4 <= deg; k += 4) {
        int r0 = cposL[start + k];
        int r1 = cposL[start + k + 1];
        int r2 = cposL[start + k + 2];
        int r3 = cposL[start + k + 3];
        s0 += __half2float(PhL[(size_t)r0 * 64 + lane]);
        s1 += __half2float(PhL[(size_t)r1 * 64 + lane]);
        s2 += __half2float(PhL[(size_t)r2 * 64 + lane]);
        s3 += __half2float(PhL[(size_t)r3 * 64 + lane]);
    }
    for (; k < deg; k++) s0 += __half2float(PhL[(size_t)cposL[start + k] * 64 + lane]);
    float s = (s0 + s1) + (s2 + s3);
    s /= (float)(deg > 1 ? deg : 1);
    s += f2row[lane] + BiasB.p[l][lane];
    f2row[lane] = fmaxf(s, 0.f);
}

// ---------------- readout: run-accumulated graph mean sums ----------------
__launch_bounds__(256)
__global__ void k_read(const float* __restrict__ f2, P5i Batch,
                       float* __restrict__ hsum, float* __restrict__ gcnt) {
    const int RC[5] = {0, 1250, 1875, 2188, 2345};
    int t = threadIdx.x;
    int lane = t & 63;
    int w = blockIdx.x * 4 + (t >> 6);
    if (w >= 2424) return;
    int l = (w >= 2345) ? 4 : (w >= 2188) ? 3 : (w >= 1875) ? 2 : (w >= 1250) ? 1 : 0;
    int base = (w - RC[l]) * 16;
    int Nl = cN[l];
    int nn = Nl - base; if (nn > 16) nn = 16;
    const int* batch = Batch.p[l];
    const float* fb = f2 + (size_t)(cNOFF[l] + base) * 64;
    int curg = -1; float hacc = 0.f; int crun = 0;
    for (int j = 0; j < nn; j++) {
        int g = batch[base + j];
        if (g != curg) {
            if (curg >= 0) {
                atomicAdd(&hsum[curg * 320 + l * 64 + lane], hacc);
                if (lane == 0) atomicAdd(&gcnt[l * 64 + curg], (float)crun);
            }
            curg = g; hacc = 0.f; crun = 0;
        }
        hacc += fb[(size_t)j * 64 + lane];
        crun++;
    }
    if (curg >= 0) {
        atomicAdd(&hsum[curg * 320 + l * 64 + lane], hacc);
        if (lane == 0) atomicAdd(&gcnt[l * 64 + curg], (float)crun);
    }
}

// ---------------- FC + log_softmax: one block per graph ----------------
__global__ void fc_kernel(const float* __restrict__ hsum, const float* __restrict__ gcnt,
                          const float* __restrict__ fcw, const float* __restrict__ fcb,
                          float* __restrict__ out) {
    int g = blockIdx.x;
    int lane = threadIdx.x;  // 64
    float partial[10];
#pragma unroll
    for (int t = 0; t < 10; t++) partial[t] = 0.f;
#pragma unroll
    for (int k = 0; k < 5; k++) {
        int j = k * 64 + lane;
        float c = fmaxf(gcnt[k * 64 + g], 1.f);
        float h = hsum[g * 320 + j] / c;
        const float* fw = fcw + j * 10;
#pragma unroll
        for (int t = 0; t < 10; t++) partial[t] = fmaf(h, fw[t], partial[t]);
    }
#pragma unroll
    for (int off = 32; off >= 1; off >>= 1)
#pragma unroll
        for (int t = 0; t < 10; t++) partial[t] += __shfl_xor(partial[t], off, 64);
    if (lane == 0) {
        float logit[10];
#pragma unroll
        for (int t = 0; t < 10; t++) logit[t] = partial[t] + fcb[t];
        float m = logit[0];
#pragma unroll
        for (int t = 1; t < 10; t++) m = fmaxf(m, logit[t]);
        float sum = 0.f;
#pragma unroll
        for (int t = 0; t < 10; t++) sum += expf(logit[t] - m);
        float lse = m + logf(sum);
#pragma unroll
        for (int t = 0; t < 10; t++) out[g * 10 + t] = logit[t] - lse;
    }
}

extern "C" void kernel_launch(void* const* d_in, const int* in_sizes, int n_in,
                              void* d_out, int out_size, void* d_ws, size_t ws_size,
                              hipStream_t stream) {
    int* wsI = (int*)d_ws;
    int*   dcnt  = wsI;                          // 38750
    int*   rank  = dcnt + 38750;                 // 38750
    float* hsum  = (float*)(rank + 38750);       // 20480  (hsum[g*320 + l*64 + lane])
    float* gcnt  = hsum + 20480;                 // 320
    float* f2    = gcnt + 320;                   // 2,480,000 (R from rgemm)
    int*   dbase = (int*)(f2 + 2480000);         // 38750
    int*   bsum  = dbase + 38750;                // 160
    int*   boff  = bsum + 160;                   // 160
    int*   cpos  = boff + 160;                   // 620000
    int*   bb    = cpos + 620000;                // 155136
    int*   csPad = bb + 155136;                  // 320
    int*   cellTot = csPad + 320;                // 320
    int*   cot   = cellTot + 320;                // 10008
    int4*  cbrec = (int4*)(((size_t)(cot + 10008) + 15) & ~(size_t)15);   // 640512 recs
    int4*  darec = cbrec + 640512;               // 620000 recs
    ushortT* f1bf = (ushortT*)(darec + 620000);  // 1,840,000 ushorts
    uint4* whi   = (uint4*)(((size_t)(f1bf + 1840000) + 15) & ~(size_t)15);  // 288000
    uint4* rbsw  = whi + 288000;                 // 2304
    uint4* wasw  = rbsw + 2304;                  // 4608
    __half* Ph   = (__half*)(wasw + 4608);       // 640512 rows of 64 (~82MB, DISJOINT per level)

    hipMemsetAsync(dcnt, 0, (size_t)(38750 * 2 + 20480 + 320) * sizeof(int), stream);

    P5f PS, X, WA, RootA, BiasA, WB, RootB, BiasB;
    P5i EI, Batch;
    for (int l = 0; l < 5; l++) {
        const int b = l * 10;
        X.p[l]     = (const float*)d_in[b + 0];
        PS.p[l]    = (const float*)d_in[b + 1];
        EI.p[l]    = (const int*)d_in[b + 2];
        Batch.p[l] = (const int*)d_in[b + 3];
        WA.p[l]    = (const float*)d_in[b + 4];
        RootA.p[l] = (const float*)d_in[b + 5];
        BiasA.p[l] = (const float*)d_in[b + 6];
        WB.p[l]    = (const float*)d_in[b + 7];
        RootB.p[l] = (const float*)d_in[b + 8];
        BiasB.p[l] = (const float*)d_in[b + 9];
    }

    // prep
    k_hist<<<2424, 256, 0, stream>>>(PS, EI, dcnt, bb);
    k_cellscan<<<5, 64, 0, stream>>>(bb, csPad, cellTot, cot);
    k_nscan1<<<154, 256, 0, stream>>>(dcnt, dbase, bsum);
    k_nscan2<<<5, 64, 0, stream>>>(bsum, boff);
    k_scatter<<<2424, 256, 0, stream>>>(PS, EI, bb, csPad, dbase, boff, rank,
                                        cbrec, darec, cpos);
    k_wswz<<<1152, 256, 0, stream>>>(WB, RootB, WA, whi, rbsw, wasw);

    // conv A (all levels) -> f1bf (MFMA tail)
    conv_a_fused<<<2424, 256, 0, stream>>>(X, RootA, BiasA, darec, wasw,
                                           dbase, boff, dcnt, f1bf);

    // R = f1 @ rootb into f2 (MFMA)
    k_rgemm<<<609, 256, 0, stream>>>(f1bf, rbsw, f2);

    // conv B (ALL levels, one dispatch) -> Ph; node epilogue (ALL levels) -> f2
    conv_b_all<<<10008, 256, 0, stream>>>(f1bf, cbrec, whi, cot, csPad, cellTot, Ph);
    node_b_all<<<9688, 256, 0, stream>>>(Ph, cpos, dbase, boff, dcnt, BiasB, f2);

    // readout + FC
    k_read<<<606, 256, 0, stream>>>(f2, Batch, hsum, gcnt);
    fc_kernel<<<64, 64, 0, stream>>>(hsum, gcnt, (const float*)d_in[50], (const float*)d_in[51],
                                     (float*)d_out);
}